// Round 6
// baseline (440.494 us; speedup 1.0000x reference)
//
#include <hip/hip_runtime.h>

#define N_NODES  50000
#define N_EDGES  1600000
#define N_GRAPHS 1000
#define F_IN     92
#define WIDTH    128
#define F_OUT    64
#define CHUNK    16384       // edges per histogram chunk (2^14)
#define NBLK_E   98          // ceil(N_EDGES/CHUNK)
#define HPB      25024       // nibble-hist row pitch BYTES (50000 nibbles -> 25000B, 64-pad)
#define HWRD     6256        // HPB/4 u32 words
#define BPITCH   50048       // basep row pitch BYTES (u8 per node)
#define XPITCH   48          // u32 per packed-X row (96 bf16, rows 192B 64-aligned)

// ---- workspace layout (4-byte word offsets) ----
static const size_t CNT   = 0;         // u32[50000] in-degree
static const size_t ROWP  = 50000;     // i32[50001] (pad to 50004)
static const size_t SVAL  = 100004;    // f32[50000] per-node sum of folded edge weights
static const size_t NSRC  = 150004;    // f32[50000]
static const size_t NDST  = 200004;    // f32[50000]
static const size_t RNK8  = 250004;    // u8[1.6M] per-edge in-chunk rank (<=15)
static const size_t HD    = 650004;    // u8[98][25024] dst nibble hist
static const size_t HSR   = 1263092;   // u8[98][25024] src nibble hist
static const size_t BASEP = 1876180;   // u8[98][50048] per-chunk exclusive base
static const size_t CSR   = 3102356;   // int2[1.6M] (src, f32 w) pairs
static const size_t XB    = 6302356;   // u32[50000*48] bf16x2-packed raw features
static const size_t W01   = 8702356;   // f32[92*128]  W0@W1
static const size_t BW1   = 8714132;   // f32[128]     b0@W1
static const size_t GAGG  = 8714260;   // f32[50000*96] aggregated raw features
static const size_t HS2   = 13514260;  // u32[50000*32] bf16x2 x@W2
static const size_t AGG2  = GAGG;      // f32[50000*64] aliases GAGG (dead after layer1)
// total = 15,114,260 words = 60.5 MB

__device__ inline unsigned short f2bf(float f) {
    unsigned u = __float_as_uint(f);
    return (unsigned short)((u + 0x7fff + ((u >> 16) & 1)) >> 16);  // RN
}
__device__ inline float bflo(unsigned u) { return __uint_as_float(u << 16); }
__device__ inline float bfhi(unsigned u) { return __uint_as_float(u & 0xffff0000u); }

// K1: per-chunk LDS NIBBLE histograms. blocks [0,98): dst (+rank); [98,196): src.
// Per-(chunk,bin) count: lambda=0.33 => P(>=16) ~ 1e-21 per cell; nibble safe.
__global__ __launch_bounds__(256) void k_hist(const int* __restrict__ src,
                                              const int* __restrict__ dst,
                                              unsigned char* __restrict__ h_dst,
                                              unsigned char* __restrict__ h_src,
                                              unsigned char* __restrict__ rank8) {
    __shared__ unsigned sh[HWRD];   // 25024 B packed u4 bins
    const bool is_dst = blockIdx.x < NBLK_E;
    const int b = is_dst ? blockIdx.x : blockIdx.x - NBLK_E;
    const int e0 = b * CHUNK;
    const int ecnt = min(CHUNK, N_EDGES - e0);
    for (int i = threadIdx.x; i < HWRD; i += 256) sh[i] = 0;
    __syncthreads();
    const int* __restrict__ idx = is_dst ? dst : src;
    for (int i = threadIdx.x; i < ecnt; i += 256) {
        int v = idx[e0 + i];
        unsigned sh_amt = (v & 7) * 4;
        unsigned old = atomicAdd(&sh[v >> 3], 1u << sh_amt);
        if (is_dst) rank8[e0 + i] = (unsigned char)((old >> sh_amt) & 0xfu);
    }
    __syncthreads();
    unsigned* out = (unsigned*)((is_dst ? h_dst : h_src) + (size_t)b * HPB);
    for (int i = threadIdx.x; i < HWRD; i += 256) out[i] = sh[i];
}

// K2: pack atom_features f32[50000][92] -> bf16x2 u32[50000][48] (cols 92..95 zero)
__global__ void k_packX(const float* __restrict__ af, unsigned* __restrict__ xb) {
    int idx = blockIdx.x * blockDim.x + threadIdx.x;   // 50000*48 = 2.4M
    if (idx >= N_NODES * XPITCH) return;
    int n = idx / XPITCH, c = idx - n * XPITCH;
    unsigned v = 0;
    if (c < 46) {
        const float* p = af + (size_t)n * F_IN + 2 * c;
        v = (unsigned)f2bf(p[0]) | ((unsigned)f2bf(p[1]) << 16);
    }
    xb[idx] = v;
}

// K3: column reduce over chunks: dst nibbles -> basep (exclusive) + cnt_in + ndst;
//     src nibbles -> nsrc.
__global__ __launch_bounds__(256) void k_reduce(const unsigned char* __restrict__ h_dst,
                                                const unsigned char* __restrict__ h_src,
                                                unsigned char* __restrict__ basep,
                                                unsigned* __restrict__ cnt_in,
                                                float* __restrict__ nsrc,
                                                float* __restrict__ ndst) {
    int n = blockIdx.x * 256 + threadIdx.x;
    if (n >= N_NODES) return;
    const int byte = n >> 1;
    const int shn = (n & 1) * 4;
    unsigned run = 0;
    for (int b = 0; b < NBLK_E; ++b) {
        unsigned v = (h_dst[(size_t)b * HPB + byte] >> shn) & 0xfu;
        basep[(size_t)b * BPITCH + n] = (unsigned char)run;  // max in-deg ~90 < 256
        run += v;
    }
    cnt_in[n] = run;
    ndst[n] = rsqrtf((float)max(run, 1u));
    unsigned so = 0;
    for (int b = 0; b < NBLK_E; ++b)
        so += (h_src[(size_t)b * HPB + byte] >> shn) & 0xfu;
    nsrc[n] = rsqrtf((float)max(so, 1u));
}

// K4: single-block exclusive scan of cnt_in -> rowp (1024 thr x 49 elems)
__global__ __launch_bounds__(1024) void k_scan(const unsigned* __restrict__ cnt,
                                               int* __restrict__ rowp) {
    __shared__ int sd[1024];
    const int t = threadIdx.x;
    const int i0 = t * 49;
    const int i1 = min(i0 + 49, N_NODES);
    int s = 0;
    for (int i = i0; i < i1; ++i) s += (int)cnt[i];
    sd[t] = s;
    __syncthreads();
    for (int off = 1; off < 1024; off <<= 1) {
        int v = (t >= off) ? sd[t - off] : 0;
        __syncthreads();
        sd[t] += v;
        __syncthreads();
    }
    int run = t ? sd[t - 1] : 0;
    for (int i = i0; i < i1; ++i) { int c = (int)cnt[i]; rowp[i] = run; run += c; }
    if (t == 1023) rowp[N_NODES] = N_EDGES;
}

// K5: fill CSR, zero atomics: p = rowp[dst] + basep[chunk][dst] + rank8[e].
// Edge weight folds in nsrc[src] (row-scale commutes with right-multiplies).
__global__ void k_fill(const float* __restrict__ bl,
                       const int* __restrict__ src, const int* __restrict__ dst,
                       const unsigned char* __restrict__ rank8,
                       const unsigned char* __restrict__ basep,
                       const int* __restrict__ rowp,
                       const float* __restrict__ nsrc,
                       int2* __restrict__ csr) {
    int e = blockIdx.x * blockDim.x + threadIdx.x;
    if (e >= N_EDGES) return;
    float x = bl[3 * e + 0], y = bl[3 * e + 1], z = bl[3 * e + 2];
    int s = src[e], d = dst[e];
    float w = expf(-(x * x + y * y + z * z) * (1.0f / 64.0f)) * nsrc[s];
    int b = e >> 14;   // CHUNK = 16384
    int p = rowp[d] + (int)basep[(size_t)b * BPITCH + d] + (int)rank8[e];
    csr[p] = make_int2(s, __float_as_int(w));
}

// K6: W01 = W0 @ W1 [92x128]; block 92 computes bW1 = b0 @ W1 [128]
__global__ __launch_bounds__(128) void k_w01(const float* __restrict__ W0,
                                             const float* __restrict__ W1,
                                             const float* __restrict__ b0,
                                             float* __restrict__ w01,
                                             float* __restrict__ bw1) {
    const int t = threadIdx.x;
    const int k = blockIdx.x;
    float acc = 0.0f;
    if (k < F_IN) {
        for (int j = 0; j < WIDTH; ++j)
            acc = fmaf(W0[k * WIDTH + j], W1[j * WIDTH + t], acc);
        w01[k * WIDTH + t] = acc;
    } else {
        for (int j = 0; j < WIDTH; ++j)
            acc = fmaf(b0[j], W1[j * WIDTH + t], acc);
        bw1[t] = acc;
    }
}

// K7: G[n] = sum_in-edges X_bf16[src]*w ; S[n] = sum w   (1 wave/node, 48 active lanes)
__global__ __launch_bounds__(64) void k_gatherG(const int* __restrict__ rowp,
                                                const int2* __restrict__ csr,
                                                const unsigned* __restrict__ xb,
                                                float2* __restrict__ gf2,
                                                float* __restrict__ S) {
    __shared__ int s_s[64];
    __shared__ float s_w[64];
    const int n = blockIdx.x;
    const int tid = threadIdx.x;
    const int tc = min(tid, XPITCH - 1);   // lanes 48..63 duplicate lane 47 (discarded)
    const int start = rowp[n], end = rowp[n + 1];
    float2 acc = {0.f, 0.f};
    float ssum = 0.f;
    for (int base = start; base < end; base += 64) {
        const int m = min(64, end - base);
        if (tid < m) {
            int2 sw = csr[base + tid];
            s_s[tid] = sw.x;
            s_w[tid] = __int_as_float(sw.y);
        }
        __syncthreads();
        int j = 0;
        for (; j + 1 < m; j += 2) {
            unsigned a0 = xb[(size_t)s_s[j] * XPITCH + tc];
            unsigned a1 = xb[(size_t)s_s[j + 1] * XPITCH + tc];
            float w0 = s_w[j], w1 = s_w[j + 1];
            acc.x = fmaf(bflo(a0), w0, acc.x);
            acc.y = fmaf(bfhi(a0), w0, acc.y);
            acc.x = fmaf(bflo(a1), w1, acc.x);
            acc.y = fmaf(bfhi(a1), w1, acc.y);
            ssum += w0 + w1;
        }
        if (j < m) {
            unsigned a0 = xb[(size_t)s_s[j] * XPITCH + tc];
            float w0 = s_w[j];
            acc.x = fmaf(bflo(a0), w0, acc.x);
            acc.y = fmaf(bfhi(a0), w0, acc.y);
            ssum += w0;
        }
        __syncthreads();
    }
    if (tid < XPITCH) gf2[(size_t)n * XPITCH + tid] = acc;
    if (tid == 63) S[n] = ssum;
}

// K8: x = relu((G*ndst)@W01 + (S*ndst)*bW1 + b1);  hs2 = bf16(x@W2)
__global__ __launch_bounds__(128) void k_layer1(const float* __restrict__ g,
                                                const float* __restrict__ S,
                                                const float* __restrict__ ndst,
                                                const float* __restrict__ w01,
                                                const float* __restrict__ bw1,
                                                const float* __restrict__ b1,
                                                const float* __restrict__ W2,
                                                unsigned short* __restrict__ hs2h) {
    __shared__ float a_t[8][96];
    __shared__ float x_t[8][WIDTH];
    const int row0 = blockIdx.x * 8;
    const int tid = threadIdx.x;
    for (int i = tid; i < 8 * 96; i += 128) {
        int r = i / 96, k = i - r * 96;
        a_t[r][k] = g[(size_t)(row0 + r) * 96 + k] * ndst[row0 + r];
    }
    __syncthreads();
    float acc[8];
    const float bb = b1[tid], bw = bw1[tid];
#pragma unroll
    for (int r = 0; r < 8; ++r)
        acc[r] = fmaf(S[row0 + r] * ndst[row0 + r], bw, bb);
    for (int k = 0; k < F_IN; ++k) {
        const float w = w01[k * WIDTH + tid];
#pragma unroll
        for (int r = 0; r < 8; ++r) acc[r] = fmaf(a_t[r][k], w, acc[r]);
    }
#pragma unroll
    for (int r = 0; r < 8; ++r)
        x_t[r][tid] = fmaxf(acc[r], 0.0f);
    __syncthreads();
    const int c2 = tid & 63;
    const int rb = tid >> 6;
    float acc2[4] = {0.f, 0.f, 0.f, 0.f};
    for (int k = 0; k < WIDTH; ++k) {
        const float w = W2[k * F_OUT + c2];
#pragma unroll
        for (int j = 0; j < 4; ++j) acc2[j] = fmaf(x_t[rb + 2 * j][k], w, acc2[j]);
    }
#pragma unroll
    for (int j = 0; j < 4; ++j)
        hs2h[(size_t)(row0 + rb + 2 * j) * F_OUT + c2] = f2bf(acc2[j]);
}

// K9: agg2[n] = sum_in-edges hs2[src]*w  (1 wave/node, 2 edges/iter, 32 lanes each)
__global__ __launch_bounds__(64) void k_gather2(const int* __restrict__ rowp,
                                                const int2* __restrict__ csr,
                                                const unsigned* __restrict__ hs2u,
                                                float2* __restrict__ agg2f2) {
    __shared__ int s_s[64];
    __shared__ float s_w[64];
    const int n = blockIdx.x;
    const int tid = threadIdx.x;
    const int c = tid & 31;
    const int half = tid >> 5;
    const int start = rowp[n], end = rowp[n + 1];
    float2 acc = {0.f, 0.f};
    for (int base = start; base < end; base += 64) {
        const int m = min(64, end - base);
        if (tid < m) {
            int2 sw = csr[base + tid];
            s_s[tid] = sw.x;
            s_w[tid] = __int_as_float(sw.y);
        }
        __syncthreads();
        int j = 0;
        for (; j + 1 < m; j += 2) {
            int e = j + half;
            unsigned a = hs2u[(size_t)s_s[e] * 32 + c];
            float w = s_w[e];
            acc.x = fmaf(bflo(a), w, acc.x);
            acc.y = fmaf(bfhi(a), w, acc.y);
        }
        if (j < m && half == 0) {
            unsigned a = hs2u[(size_t)s_s[j] * 32 + c];
            float w = s_w[j];
            acc.x = fmaf(bflo(a), w, acc.x);
            acc.y = fmaf(bfhi(a), w, acc.y);
        }
        __syncthreads();
    }
    acc.x += __shfl_xor(acc.x, 32);
    acc.y += __shfl_xor(acc.y, 32);
    if (tid < 32) agg2f2[(size_t)n * 32 + tid] = acc;
}

// K10: per-graph mean pooling via sorted-gid segments
__global__ __launch_bounds__(64) void k_pool(const float* __restrict__ agg2,
                                             const float* __restrict__ ndst,
                                             const float* __restrict__ b2,
                                             const int* __restrict__ gid,
                                             float* __restrict__ out) {
    const int g = blockIdx.x;
    const int t = threadIdx.x;
    int lo = 0, hi = N_NODES;
    while (lo < hi) { int mid = (lo + hi) >> 1; if (gid[mid] < g) lo = mid + 1; else hi = mid; }
    const int start = lo;
    hi = N_NODES;
    while (lo < hi) { int mid = (lo + hi) >> 1; if (gid[mid] < g + 1) lo = mid + 1; else hi = mid; }
    const int end = lo;
    float sum = 0.0f;
    for (int n = start; n < end; ++n)
        sum = fmaf(agg2[n * F_OUT + t], ndst[n], sum);
    out[g * F_OUT + t] = (end > start) ? (sum / (float)(end - start) + b2[t]) : 0.0f;
}

extern "C" void kernel_launch(void* const* d_in, const int* in_sizes, int n_in,
                              void* d_out, int out_size, void* d_ws, size_t ws_size,
                              hipStream_t stream) {
    const float* af  = (const float*)d_in[0];
    const float* bl  = (const float*)d_in[1];
    const int*   src = (const int*)d_in[2];
    const int*   dst = (const int*)d_in[3];
    const int*   gid = (const int*)d_in[4];
    const float* W0  = (const float*)d_in[5];
    const float* b0  = (const float*)d_in[6];
    const float* W1  = (const float*)d_in[7];
    const float* b1  = (const float*)d_in[8];
    const float* W2  = (const float*)d_in[9];
    const float* b2  = (const float*)d_in[10];
    float* out = (float*)d_out;
    float* ws  = (float*)d_ws;

    unsigned*       cnt_in = (unsigned*)(ws + CNT);
    int*            rowp   = (int*)(ws + ROWP);
    float*          S      = ws + SVAL;
    float*          nsrc   = ws + NSRC;
    float*          ndst   = ws + NDST;
    unsigned char*  rank8  = (unsigned char*)(ws + RNK8);
    unsigned char*  h_dst  = (unsigned char*)(ws + HD);
    unsigned char*  h_src  = (unsigned char*)(ws + HSR);
    unsigned char*  basep  = (unsigned char*)(ws + BASEP);
    int2*           csr    = (int2*)(ws + CSR);
    unsigned*       xb     = (unsigned*)(ws + XB);
    float*          w01    = ws + W01;
    float*          bw1    = ws + BW1;
    float*          g      = ws + GAGG;
    unsigned*       hs2u   = (unsigned*)(ws + HS2);
    unsigned short* hs2h   = (unsigned short*)(ws + HS2);
    float*          agg2   = ws + AGG2;   // aliases GAGG (dead after k_layer1)

    const int EB = (N_EDGES + 255) / 256;
    k_hist<<<2 * NBLK_E, 256, 0, stream>>>(src, dst, h_dst, h_src, rank8);
    k_packX<<<(N_NODES * XPITCH) / 256, 256, 0, stream>>>(af, xb);
    k_reduce<<<(N_NODES + 255) / 256, 256, 0, stream>>>(h_dst, h_src, basep, cnt_in, nsrc, ndst);
    k_scan<<<1, 1024, 0, stream>>>(cnt_in, rowp);
    k_fill<<<EB, 256, 0, stream>>>(bl, src, dst, rank8, basep, rowp, nsrc, csr);
    k_w01<<<F_IN + 1, 128, 0, stream>>>(W0, W1, b0, w01, bw1);
    k_gatherG<<<N_NODES, 64, 0, stream>>>(rowp, csr, xb, (float2*)g, S);
    k_layer1<<<N_NODES / 8, 128, 0, stream>>>(g, S, ndst, w01, bw1, b1, W2, hs2h);
    k_gather2<<<N_NODES, 64, 0, stream>>>(rowp, csr, hs2u, (float2*)agg2);
    k_pool<<<N_GRAPHS, 64, 0, stream>>>(agg2, ndst, b2, gid, out);
}

// Round 7
// 367.063 us; speedup vs baseline: 1.2001x; 1.2001x over previous
//
#include <hip/hip_runtime.h>

#define N_NODES  50000
#define N_EDGES  1600000
#define N_GRAPHS 1000
#define F_IN     92
#define WIDTH    128
#define F_OUT    64
#define NBLK_SCAN 196        // ceil(50000/256)
#define CHUNK    16384       // edges per histogram chunk (2^14)
#define NBLK_E   98          // ceil(N_EDGES/CHUNK)
#define HPB      25024       // nibble-hist row pitch BYTES (50000 nibbles -> 25000B, 64-pad)
#define HWRD     6256        // HPB/4 u32 words
#define BPITCH   50048       // basep row pitch BYTES (u8 per node)
#define XPITCH   48          // u32 per packed-X row (96 bf16, rows 192B 64-aligned)

// ---- workspace layout (4-byte word offsets) ----
static const size_t CNT   = 0;         // u32[50000] in-degree
static const size_t ROWP  = 50000;     // i32[50001] (pad to 50004)
static const size_t SVAL  = 100004;    // f32[50000] per-node sum of folded edge weights
static const size_t NSRC  = 150004;    // f32[50000]
static const size_t NDST  = 200004;    // f32[50000]
static const size_t BSUM  = 250004;    // i32[256] scan block sums
static const size_t RNK8  = 250260;    // u8[1.6M] per-edge in-chunk rank (<=15)
static const size_t HD    = 650260;    // u8[98][25024] dst nibble hist
static const size_t HSR   = 1263348;   // u8[98][25024] src nibble hist
static const size_t BASEP = 1876436;   // u8[98][50048] per-chunk exclusive base
static const size_t CSR   = 3102612;   // int2[1.6M] (src, f32 w) pairs
static const size_t XB    = 6302612;   // u32[50000*48] bf16x2-packed raw features
static const size_t W01   = 8702612;   // f32[92*128]  W0@W1
static const size_t BW1   = 8714388;   // f32[128]     b0@W1
static const size_t GAGG  = 8714516;   // f32[50000*96] aggregated raw features
static const size_t HS2   = 13514516;  // u32[50000*32] bf16x2 x@W2
static const size_t AGG2  = GAGG;      // f32[50000*64] aliases GAGG (dead after layer1)
// total = 15,114,516 words = 60.5 MB

__device__ inline unsigned short f2bf(float f) {
    unsigned u = __float_as_uint(f);
    return (unsigned short)((u + 0x7fff + ((u >> 16) & 1)) >> 16);  // RN
}
__device__ inline float bflo(unsigned u) { return __uint_as_float(u << 16); }
__device__ inline float bfhi(unsigned u) { return __uint_as_float(u & 0xffff0000u); }

// K1: per-chunk LDS NIBBLE histograms. blocks [0,98): dst (+rank); [98,196): src.
__global__ __launch_bounds__(256) void k_hist(const int* __restrict__ src,
                                              const int* __restrict__ dst,
                                              unsigned char* __restrict__ h_dst,
                                              unsigned char* __restrict__ h_src,
                                              unsigned char* __restrict__ rank8) {
    __shared__ unsigned sh[HWRD];   // 25024 B packed u4 bins
    const bool is_dst = blockIdx.x < NBLK_E;
    const int b = is_dst ? blockIdx.x : blockIdx.x - NBLK_E;
    const int e0 = b * CHUNK;
    const int ecnt = min(CHUNK, N_EDGES - e0);
    for (int i = threadIdx.x; i < HWRD; i += 256) sh[i] = 0;
    __syncthreads();
    const int* __restrict__ idx = is_dst ? dst : src;
    for (int i = threadIdx.x; i < ecnt; i += 256) {
        int v = idx[e0 + i];
        unsigned sh_amt = (v & 7) * 4;
        unsigned old = atomicAdd(&sh[v >> 3], 1u << sh_amt);
        if (is_dst) rank8[e0 + i] = (unsigned char)((old >> sh_amt) & 0xfu);
    }
    __syncthreads();
    unsigned* out = (unsigned*)((is_dst ? h_dst : h_src) + (size_t)b * HPB);
    for (int i = threadIdx.x; i < HWRD; i += 256) out[i] = sh[i];
}

// K2: pack atom_features f32[50000][92] -> bf16x2 u32[50000][48] (cols 92..95 zero)
__global__ void k_packX(const float* __restrict__ af, unsigned* __restrict__ xb) {
    int idx = blockIdx.x * blockDim.x + threadIdx.x;   // 50000*48 = 2.4M
    if (idx >= N_NODES * XPITCH) return;
    int n = idx / XPITCH, c = idx - n * XPITCH;
    unsigned v = 0;
    if (c < 46) {
        const float* p = af + (size_t)n * F_IN + 2 * c;
        v = (unsigned)f2bf(p[0]) | ((unsigned)f2bf(p[1]) << 16);
    }
    xb[idx] = v;
}

// K3: column reduce over chunks: dst nibbles -> basep (exclusive) + cnt_in + ndst;
//     src nibbles -> nsrc.
__global__ __launch_bounds__(256) void k_reduce(const unsigned char* __restrict__ h_dst,
                                                const unsigned char* __restrict__ h_src,
                                                unsigned char* __restrict__ basep,
                                                unsigned* __restrict__ cnt_in,
                                                float* __restrict__ nsrc,
                                                float* __restrict__ ndst) {
    int n = blockIdx.x * 256 + threadIdx.x;
    if (n >= N_NODES) return;
    const int byte = n >> 1;
    const int shn = (n & 1) * 4;
    unsigned run = 0;
    for (int b = 0; b < NBLK_E; ++b) {
        unsigned v = (h_dst[(size_t)b * HPB + byte] >> shn) & 0xfu;
        basep[(size_t)b * BPITCH + n] = (unsigned char)run;  // max in-deg ~90 < 256
        run += v;
    }
    cnt_in[n] = run;
    ndst[n] = rsqrtf((float)max(run, 1u));
    unsigned so = 0;
    for (int b = 0; b < NBLK_E; ++b)
        so += (h_src[(size_t)b * HPB + byte] >> shn) & 0xfu;
    nsrc[n] = rsqrtf((float)max(so, 1u));
}

// K4a: per-block exclusive scan of cnt_in -> rowp + block sums  [196 blocks]
__global__ __launch_bounds__(256) void k_scanA(const unsigned* __restrict__ cnt_in,
                                               int* __restrict__ rowp,
                                               int* __restrict__ bsum) {
    __shared__ int sd[256];
    const int t = threadIdx.x;
    const int i = blockIdx.x * 256 + t;
    int v = (i < N_NODES) ? (int)cnt_in[i] : 0;
    sd[t] = v;
    __syncthreads();
    for (int off = 1; off < 256; off <<= 1) {
        int add = (t >= off) ? sd[t - off] : 0;
        __syncthreads();
        sd[t] += add;
        __syncthreads();
    }
    if (i < N_NODES) rowp[i] = sd[t] - v;
    if (t == 255) bsum[blockIdx.x] = sd[255];
}

// K4b: exclusive scan of block sums  [1 block]
__global__ __launch_bounds__(256) void k_scanB(int* __restrict__ bsum) {
    __shared__ int sd[256];
    const int t = threadIdx.x;
    int v = (t < NBLK_SCAN) ? bsum[t] : 0;
    sd[t] = v;
    __syncthreads();
    for (int off = 1; off < 256; off <<= 1) {
        int add = (t >= off) ? sd[t - off] : 0;
        __syncthreads();
        sd[t] += add;
        __syncthreads();
    }
    if (t < NBLK_SCAN) bsum[t] = sd[t] - v;
}

// K4c: finalize rowp
__global__ void k_scanC(int* __restrict__ rowp, const int* __restrict__ bsum) {
    int i = blockIdx.x * blockDim.x + threadIdx.x;
    if (i >= N_NODES) return;
    rowp[i] = rowp[i] + bsum[i >> 8];
    if (i == 0) rowp[N_NODES] = N_EDGES;
}

// K5: fill CSR, zero atomics: p = rowp[dst] + basep[chunk][dst] + rank8[e].
// Edge weight folds in nsrc[src] (row-scale commutes with right-multiplies).
__global__ void k_fill(const float* __restrict__ bl,
                       const int* __restrict__ src, const int* __restrict__ dst,
                       const unsigned char* __restrict__ rank8,
                       const unsigned char* __restrict__ basep,
                       const int* __restrict__ rowp,
                       const float* __restrict__ nsrc,
                       int2* __restrict__ csr) {
    int e = blockIdx.x * blockDim.x + threadIdx.x;
    if (e >= N_EDGES) return;
    float x = bl[3 * e + 0], y = bl[3 * e + 1], z = bl[3 * e + 2];
    int s = src[e], d = dst[e];
    float w = expf(-(x * x + y * y + z * z) * (1.0f / 64.0f)) * nsrc[s];
    int b = e >> 14;   // CHUNK = 16384
    int p = rowp[d] + (int)basep[(size_t)b * BPITCH + d] + (int)rank8[e];
    csr[p] = make_int2(s, __float_as_int(w));
}

// K6: W01 = W0 @ W1 [92x128]; block 92 computes bW1 = b0 @ W1 [128]
__global__ __launch_bounds__(128) void k_w01(const float* __restrict__ W0,
                                             const float* __restrict__ W1,
                                             const float* __restrict__ b0,
                                             float* __restrict__ w01,
                                             float* __restrict__ bw1) {
    const int t = threadIdx.x;
    const int k = blockIdx.x;
    float acc = 0.0f;
    if (k < F_IN) {
        for (int j = 0; j < WIDTH; ++j)
            acc = fmaf(W0[k * WIDTH + j], W1[j * WIDTH + t], acc);
        w01[k * WIDTH + t] = acc;
    } else {
        for (int j = 0; j < WIDTH; ++j)
            acc = fmaf(b0[j], W1[j * WIDTH + t], acc);
        bw1[t] = acc;
    }
}

// K7: G[n] = sum_in-edges X_bf16[src]*w ; S[n] = sum w   (1 wave/node, 48 active lanes)
__global__ __launch_bounds__(64) void k_gatherG(const int* __restrict__ rowp,
                                                const int2* __restrict__ csr,
                                                const unsigned* __restrict__ xb,
                                                float2* __restrict__ gf2,
                                                float* __restrict__ S) {
    __shared__ int s_s[64];
    __shared__ float s_w[64];
    const int n = blockIdx.x;
    const int tid = threadIdx.x;
    const int tc = min(tid, XPITCH - 1);   // lanes 48..63 duplicate lane 47 (discarded)
    const int start = rowp[n], end = rowp[n + 1];
    float2 acc = {0.f, 0.f};
    float ssum = 0.f;
    for (int base = start; base < end; base += 64) {
        const int m = min(64, end - base);
        if (tid < m) {
            int2 sw = csr[base + tid];
            s_s[tid] = sw.x;
            s_w[tid] = __int_as_float(sw.y);
        }
        __syncthreads();
        int j = 0;
        for (; j + 1 < m; j += 2) {
            unsigned a0 = xb[(size_t)s_s[j] * XPITCH + tc];
            unsigned a1 = xb[(size_t)s_s[j + 1] * XPITCH + tc];
            float w0 = s_w[j], w1 = s_w[j + 1];
            acc.x = fmaf(bflo(a0), w0, acc.x);
            acc.y = fmaf(bfhi(a0), w0, acc.y);
            acc.x = fmaf(bflo(a1), w1, acc.x);
            acc.y = fmaf(bfhi(a1), w1, acc.y);
            ssum += w0 + w1;
        }
        if (j < m) {
            unsigned a0 = xb[(size_t)s_s[j] * XPITCH + tc];
            float w0 = s_w[j];
            acc.x = fmaf(bflo(a0), w0, acc.x);
            acc.y = fmaf(bfhi(a0), w0, acc.y);
            ssum += w0;
        }
        __syncthreads();
    }
    if (tid < XPITCH) gf2[(size_t)n * XPITCH + tid] = acc;
    if (tid == 63) S[n] = ssum;
}

// K8: x = relu((G*ndst)@W01 + (S*ndst)*bW1 + b1);  hs2 = bf16(x@W2)
__global__ __launch_bounds__(128) void k_layer1(const float* __restrict__ g,
                                                const float* __restrict__ S,
                                                const float* __restrict__ ndst,
                                                const float* __restrict__ w01,
                                                const float* __restrict__ bw1,
                                                const float* __restrict__ b1,
                                                const float* __restrict__ W2,
                                                unsigned short* __restrict__ hs2h) {
    __shared__ float a_t[8][96];
    __shared__ float x_t[8][WIDTH];
    const int row0 = blockIdx.x * 8;
    const int tid = threadIdx.x;
    for (int i = tid; i < 8 * 96; i += 128) {
        int r = i / 96, k = i - r * 96;
        a_t[r][k] = g[(size_t)(row0 + r) * 96 + k] * ndst[row0 + r];
    }
    __syncthreads();
    float acc[8];
    const float bb = b1[tid], bw = bw1[tid];
#pragma unroll
    for (int r = 0; r < 8; ++r)
        acc[r] = fmaf(S[row0 + r] * ndst[row0 + r], bw, bb);
    for (int k = 0; k < F_IN; ++k) {
        const float w = w01[k * WIDTH + tid];
#pragma unroll
        for (int r = 0; r < 8; ++r) acc[r] = fmaf(a_t[r][k], w, acc[r]);
    }
#pragma unroll
    for (int r = 0; r < 8; ++r)
        x_t[r][tid] = fmaxf(acc[r], 0.0f);
    __syncthreads();
    const int c2 = tid & 63;
    const int rb = tid >> 6;
    float acc2[4] = {0.f, 0.f, 0.f, 0.f};
    for (int k = 0; k < WIDTH; ++k) {
        const float w = W2[k * F_OUT + c2];
#pragma unroll
        for (int j = 0; j < 4; ++j) acc2[j] = fmaf(x_t[rb + 2 * j][k], w, acc2[j]);
    }
#pragma unroll
    for (int j = 0; j < 4; ++j)
        hs2h[(size_t)(row0 + rb + 2 * j) * F_OUT + c2] = f2bf(acc2[j]);
}

// K9: agg2[n] = sum_in-edges hs2[src]*w  (1 wave/node, 2 edges/iter, 32 lanes each)
__global__ __launch_bounds__(64) void k_gather2(const int* __restrict__ rowp,
                                                const int2* __restrict__ csr,
                                                const unsigned* __restrict__ hs2u,
                                                float2* __restrict__ agg2f2) {
    __shared__ int s_s[64];
    __shared__ float s_w[64];
    const int n = blockIdx.x;
    const int tid = threadIdx.x;
    const int c = tid & 31;
    const int half = tid >> 5;
    const int start = rowp[n], end = rowp[n + 1];
    float2 acc = {0.f, 0.f};
    for (int base = start; base < end; base += 64) {
        const int m = min(64, end - base);
        if (tid < m) {
            int2 sw = csr[base + tid];
            s_s[tid] = sw.x;
            s_w[tid] = __int_as_float(sw.y);
        }
        __syncthreads();
        int j = 0;
        for (; j + 1 < m; j += 2) {
            int e = j + half;
            unsigned a = hs2u[(size_t)s_s[e] * 32 + c];
            float w = s_w[e];
            acc.x = fmaf(bflo(a), w, acc.x);
            acc.y = fmaf(bfhi(a), w, acc.y);
        }
        if (j < m && half == 0) {
            unsigned a = hs2u[(size_t)s_s[j] * 32 + c];
            float w = s_w[j];
            acc.x = fmaf(bflo(a), w, acc.x);
            acc.y = fmaf(bfhi(a), w, acc.y);
        }
        __syncthreads();
    }
    acc.x += __shfl_xor(acc.x, 32);
    acc.y += __shfl_xor(acc.y, 32);
    if (tid < 32) agg2f2[(size_t)n * 32 + tid] = acc;
}

// K10: per-graph mean pooling via sorted-gid segments
__global__ __launch_bounds__(64) void k_pool(const float* __restrict__ agg2,
                                             const float* __restrict__ ndst,
                                             const float* __restrict__ b2,
                                             const int* __restrict__ gid,
                                             float* __restrict__ out) {
    const int g = blockIdx.x;
    const int t = threadIdx.x;
    int lo = 0, hi = N_NODES;
    while (lo < hi) { int mid = (lo + hi) >> 1; if (gid[mid] < g) lo = mid + 1; else hi = mid; }
    const int start = lo;
    hi = N_NODES;
    while (lo < hi) { int mid = (lo + hi) >> 1; if (gid[mid] < g + 1) lo = mid + 1; else hi = mid; }
    const int end = lo;
    float sum = 0.0f;
    for (int n = start; n < end; ++n)
        sum = fmaf(agg2[n * F_OUT + t], ndst[n], sum);
    out[g * F_OUT + t] = (end > start) ? (sum / (float)(end - start) + b2[t]) : 0.0f;
}

extern "C" void kernel_launch(void* const* d_in, const int* in_sizes, int n_in,
                              void* d_out, int out_size, void* d_ws, size_t ws_size,
                              hipStream_t stream) {
    const float* af  = (const float*)d_in[0];
    const float* bl  = (const float*)d_in[1];
    const int*   src = (const int*)d_in[2];
    const int*   dst = (const int*)d_in[3];
    const int*   gid = (const int*)d_in[4];
    const float* W0  = (const float*)d_in[5];
    const float* b0  = (const float*)d_in[6];
    const float* W1  = (const float*)d_in[7];
    const float* b1  = (const float*)d_in[8];
    const float* W2  = (const float*)d_in[9];
    const float* b2  = (const float*)d_in[10];
    float* out = (float*)d_out;
    float* ws  = (float*)d_ws;

    unsigned*       cnt_in = (unsigned*)(ws + CNT);
    int*            rowp   = (int*)(ws + ROWP);
    float*          S      = ws + SVAL;
    float*          nsrc   = ws + NSRC;
    float*          ndst   = ws + NDST;
    int*            bsum   = (int*)(ws + BSUM);
    unsigned char*  rank8  = (unsigned char*)(ws + RNK8);
    unsigned char*  h_dst  = (unsigned char*)(ws + HD);
    unsigned char*  h_src  = (unsigned char*)(ws + HSR);
    unsigned char*  basep  = (unsigned char*)(ws + BASEP);
    int2*           csr    = (int2*)(ws + CSR);
    unsigned*       xb     = (unsigned*)(ws + XB);
    float*          w01    = ws + W01;
    float*          bw1    = ws + BW1;
    float*          g      = ws + GAGG;
    unsigned*       hs2u   = (unsigned*)(ws + HS2);
    unsigned short* hs2h   = (unsigned short*)(ws + HS2);
    float*          agg2   = ws + AGG2;   // aliases GAGG (dead after k_layer1)

    const int EB = (N_EDGES + 255) / 256;
    k_hist<<<2 * NBLK_E, 256, 0, stream>>>(src, dst, h_dst, h_src, rank8);
    k_packX<<<(N_NODES * XPITCH) / 256, 256, 0, stream>>>(af, xb);
    k_reduce<<<(N_NODES + 255) / 256, 256, 0, stream>>>(h_dst, h_src, basep, cnt_in, nsrc, ndst);
    k_scanA<<<NBLK_SCAN, 256, 0, stream>>>(cnt_in, rowp, bsum);
    k_scanB<<<1, 256, 0, stream>>>(bsum);
    k_scanC<<<NBLK_SCAN, 256, 0, stream>>>(rowp, bsum);
    k_fill<<<EB, 256, 0, stream>>>(bl, src, dst, rank8, basep, rowp, nsrc, csr);
    k_w01<<<F_IN + 1, 128, 0, stream>>>(W0, W1, b0, w01, bw1);
    k_gatherG<<<N_NODES, 64, 0, stream>>>(rowp, csr, xb, (float2*)g, S);
    k_layer1<<<N_NODES / 8, 128, 0, stream>>>(g, S, ndst, w01, bw1, b1, W2, hs2h);
    k_gather2<<<N_NODES, 64, 0, stream>>>(rowp, csr, hs2u, (float2*)agg2);
    k_pool<<<N_GRAPHS, 64, 0, stream>>>(agg2, ndst, b2, gid, out);
}

// Round 8
// 356.798 us; speedup vs baseline: 1.2346x; 1.0288x over previous
//
#include <hip/hip_runtime.h>

#define N_NODES  50000
#define N_EDGES  1600000
#define N_GRAPHS 1000
#define F_IN     92
#define WIDTH    128
#define F_OUT    64
#define NBLK_SCAN 196        // ceil(50000/256)
#define CHUNK    16384       // edges per histogram chunk (2^14)
#define NBLK_E   98          // ceil(N_EDGES/CHUNK)
#define HPB      25024       // nibble-hist row pitch BYTES
#define HWRD     6256        // HPB/4 u32 words
#define BPITCH   50048       // basep row pitch BYTES (u8 per node)
#define XPITCH   48          // u32 per packed-X row (96 bf16, rows 192B)

// ---- workspace layout (4-byte word offsets) ----
static const size_t ROWP  = 50000;     // i32[50001]
static const size_t SVAL  = 100004;    // f32[50000]
static const size_t NSRC  = 150004;    // f32[50000]
static const size_t NDST  = 200004;    // f32[50000]
static const size_t BSUM  = 250004;    // i32[256]
static const size_t RNK8  = 250260;    // u8[1.6M]
static const size_t HD    = 650260;    // u8[98][25024] dst nibble hist
static const size_t HSR   = 1263348;   // u8[98][25024] src nibble hist
static const size_t BASEP = 1876436;   // u8[98][50048]
static const size_t CSR   = 3102612;   // int2[1.6M]
static const size_t XB    = 6302612;   // u32[50000*48]
static const size_t W01   = 8702612;   // f32[92*128]
static const size_t BW1   = 8714388;   // f32[128]
static const size_t GAGG  = 8714516;   // f32[50000*96]
static const size_t HS2   = 13514516;  // u32[50000*32]
static const size_t AGG2  = GAGG;      // aliases GAGG (dead after layer1)

__device__ inline unsigned short f2bf(float f) {
    unsigned u = __float_as_uint(f);
    return (unsigned short)((u + 0x7fff + ((u >> 16) & 1)) >> 16);  // RN
}
__device__ inline float bflo(unsigned u) { return __uint_as_float(u << 16); }
__device__ inline float bfhi(unsigned u) { return __uint_as_float(u & 0xffff0000u); }

// K1: per-chunk LDS NIBBLE histograms. blocks [0,98): dst (+rank); [98,196): src.
__global__ __launch_bounds__(256) void k_hist(const int* __restrict__ src,
                                              const int* __restrict__ dst,
                                              unsigned char* __restrict__ h_dst,
                                              unsigned char* __restrict__ h_src,
                                              unsigned char* __restrict__ rank8) {
    __shared__ unsigned sh[HWRD];
    const bool is_dst = blockIdx.x < NBLK_E;
    const int b = is_dst ? blockIdx.x : blockIdx.x - NBLK_E;
    const int e0 = b * CHUNK;
    const int ecnt = min(CHUNK, N_EDGES - e0);
    for (int i = threadIdx.x; i < HWRD; i += 256) sh[i] = 0;
    __syncthreads();
    const int* __restrict__ idx = is_dst ? dst : src;
    for (int i = threadIdx.x; i < ecnt; i += 256) {
        int v = idx[e0 + i];
        unsigned sh_amt = (v & 7) * 4;
        unsigned old = atomicAdd(&sh[v >> 3], 1u << sh_amt);
        if (is_dst) rank8[e0 + i] = (unsigned char)((old >> sh_amt) & 0xfu);
    }
    __syncthreads();
    unsigned* out = (unsigned*)((is_dst ? h_dst : h_src) + (size_t)b * HPB);
    for (int i = threadIdx.x; i < HWRD; i += 256) out[i] = sh[i];
}

// K2: pack atom_features f32[50000][92] -> bf16x2 u32[50000][48]
__global__ void k_packX(const float* __restrict__ af, unsigned* __restrict__ xb) {
    int idx = blockIdx.x * blockDim.x + threadIdx.x;
    if (idx >= N_NODES * XPITCH) return;
    int n = idx / XPITCH, c = idx - n * XPITCH;
    unsigned v = 0;
    if (c < 46) {
        const float* p = af + (size_t)n * F_IN + 2 * c;
        v = (unsigned)f2bf(p[0]) | ((unsigned)f2bf(p[1]) << 16);
    }
    xb[idx] = v;
}

// K3: column reduce over chunks + FUSED block-local scan.
// dst nibbles -> basep + in-degree; block-scan of in-degree -> rowp partial + bsum.
__global__ __launch_bounds__(256) void k_reduceScan(const unsigned char* __restrict__ h_dst,
                                                    const unsigned char* __restrict__ h_src,
                                                    unsigned char* __restrict__ basep,
                                                    int* __restrict__ rowp,
                                                    int* __restrict__ bsum,
                                                    float* __restrict__ nsrc,
                                                    float* __restrict__ ndst) {
    __shared__ int sd[256];
    const int t = threadIdx.x;
    const int n = blockIdx.x * 256 + t;
    const bool valid = n < N_NODES;
    unsigned run = 0;
    if (valid) {
        const int byte = n >> 1;
        const int shn = (n & 1) * 4;
        for (int b = 0; b < NBLK_E; ++b) {
            unsigned v = (h_dst[(size_t)b * HPB + byte] >> shn) & 0xfu;
            basep[(size_t)b * BPITCH + n] = (unsigned char)run;
            run += v;
        }
        ndst[n] = rsqrtf((float)max(run, 1u));
        unsigned so = 0;
        for (int b = 0; b < NBLK_E; ++b)
            so += (h_src[(size_t)b * HPB + byte] >> shn) & 0xfu;
        nsrc[n] = rsqrtf((float)max(so, 1u));
    }
    int v = valid ? (int)run : 0;
    sd[t] = v;
    __syncthreads();
    for (int off = 1; off < 256; off <<= 1) {
        int add = (t >= off) ? sd[t - off] : 0;
        __syncthreads();
        sd[t] += add;
        __syncthreads();
    }
    if (valid) rowp[n] = sd[t] - v;
    if (t == 255) bsum[blockIdx.x] = sd[255];
}

// K4b: exclusive scan of block sums  [1 block]
__global__ __launch_bounds__(256) void k_scanB(int* __restrict__ bsum) {
    __shared__ int sd[256];
    const int t = threadIdx.x;
    int v = (t < NBLK_SCAN) ? bsum[t] : 0;
    sd[t] = v;
    __syncthreads();
    for (int off = 1; off < 256; off <<= 1) {
        int add = (t >= off) ? sd[t - off] : 0;
        __syncthreads();
        sd[t] += add;
        __syncthreads();
    }
    if (t < NBLK_SCAN) bsum[t] = sd[t] - v;
}

// K4c: finalize rowp
__global__ void k_scanC(int* __restrict__ rowp, const int* __restrict__ bsum) {
    int i = blockIdx.x * blockDim.x + threadIdx.x;
    if (i >= N_NODES) return;
    rowp[i] = rowp[i] + bsum[i >> 8];
    if (i == 0) rowp[N_NODES] = N_EDGES;
}

// K5: fill CSR, zero atomics. Edge weight folds in nsrc[src].
__global__ void k_fill(const float* __restrict__ bl,
                       const int* __restrict__ src, const int* __restrict__ dst,
                       const unsigned char* __restrict__ rank8,
                       const unsigned char* __restrict__ basep,
                       const int* __restrict__ rowp,
                       const float* __restrict__ nsrc,
                       int2* __restrict__ csr) {
    int e = blockIdx.x * blockDim.x + threadIdx.x;
    if (e >= N_EDGES) return;
    float x = bl[3 * e + 0], y = bl[3 * e + 1], z = bl[3 * e + 2];
    int s = src[e], d = dst[e];
    float w = expf(-(x * x + y * y + z * z) * (1.0f / 64.0f)) * nsrc[s];
    int b = e >> 14;   // CHUNK = 16384
    int p = rowp[d] + (int)basep[(size_t)b * BPITCH + d] + (int)rank8[e];
    csr[p] = make_int2(s, __float_as_int(w));
}

// K6: W01 = W0 @ W1 [92x128]; block 92 computes bW1 = b0 @ W1
__global__ __launch_bounds__(128) void k_w01(const float* __restrict__ W0,
                                             const float* __restrict__ W1,
                                             const float* __restrict__ b0,
                                             float* __restrict__ w01,
                                             float* __restrict__ bw1) {
    const int t = threadIdx.x;
    const int k = blockIdx.x;
    float acc = 0.0f;
    if (k < F_IN) {
        for (int j = 0; j < WIDTH; ++j)
            acc = fmaf(W0[k * WIDTH + j], W1[j * WIDTH + t], acc);
        w01[k * WIDTH + t] = acc;
    } else {
        for (int j = 0; j < WIDTH; ++j)
            acc = fmaf(b0[j], W1[j * WIDTH + t], acc);
        bw1[t] = acc;
    }
}

// K7: G[n] = sum_in-edges X_bf16[src]*w ; S[n] = sum w
// 4 waves/block, wave-private LDS staging (no __syncthreads), 4-edge unroll.
__global__ __launch_bounds__(256) void k_gatherG(const int* __restrict__ rowp,
                                                 const int2* __restrict__ csr,
                                                 const unsigned* __restrict__ xb,
                                                 float2* __restrict__ gf2,
                                                 float* __restrict__ S) {
    __shared__ int2 sb[4][64];
    const int wid = threadIdx.x >> 6;
    const int lane = threadIdx.x & 63;
    const int n = blockIdx.x * 4 + wid;
    const int tc = min(lane, XPITCH - 1);
    int2* my = sb[wid];
    const int start = rowp[n], end = rowp[n + 1];
    float2 acc = {0.f, 0.f};
    float ssum = 0.f;
    for (int base = start; base < end; base += 64) {
        const int m = min(64, end - base);
        my[lane] = (lane < m) ? csr[base + lane] : make_int2(0, 0);
        const int mr = (m + 3) & ~3;
        for (int j = 0; j < mr; j += 4) {
            int2 e0 = my[j], e1 = my[j + 1], e2 = my[j + 2], e3 = my[j + 3];
            unsigned a0 = xb[(size_t)e0.x * XPITCH + tc];
            unsigned a1 = xb[(size_t)e1.x * XPITCH + tc];
            unsigned a2 = xb[(size_t)e2.x * XPITCH + tc];
            unsigned a3 = xb[(size_t)e3.x * XPITCH + tc];
            float w0 = __int_as_float(e0.y), w1 = __int_as_float(e1.y);
            float w2 = __int_as_float(e2.y), w3 = __int_as_float(e3.y);
            acc.x = fmaf(bflo(a0), w0, acc.x);
            acc.y = fmaf(bfhi(a0), w0, acc.y);
            acc.x = fmaf(bflo(a1), w1, acc.x);
            acc.y = fmaf(bfhi(a1), w1, acc.y);
            acc.x = fmaf(bflo(a2), w2, acc.x);
            acc.y = fmaf(bfhi(a2), w2, acc.y);
            acc.x = fmaf(bflo(a3), w3, acc.x);
            acc.y = fmaf(bfhi(a3), w3, acc.y);
            ssum += (w0 + w1) + (w2 + w3);
        }
    }
    if (lane < XPITCH) gf2[(size_t)n * XPITCH + lane] = acc;
    else if (lane == 63) S[n] = ssum;
}

// K8: x = relu((G*ndst)@W01 + (S*ndst)*bW1 + b1);  hs2 = bf16(x@W2)
__global__ __launch_bounds__(128) void k_layer1(const float* __restrict__ g,
                                                const float* __restrict__ S,
                                                const float* __restrict__ ndst,
                                                const float* __restrict__ w01,
                                                const float* __restrict__ bw1,
                                                const float* __restrict__ b1,
                                                const float* __restrict__ W2,
                                                unsigned short* __restrict__ hs2h) {
    __shared__ float a_t[8][96];
    __shared__ float x_t[8][WIDTH];
    const int row0 = blockIdx.x * 8;
    const int tid = threadIdx.x;
    for (int i = tid; i < 8 * 96; i += 128) {
        int r = i / 96, k = i - r * 96;
        a_t[r][k] = g[(size_t)(row0 + r) * 96 + k] * ndst[row0 + r];
    }
    __syncthreads();
    float acc[8];
    const float bb = b1[tid], bw = bw1[tid];
#pragma unroll
    for (int r = 0; r < 8; ++r)
        acc[r] = fmaf(S[row0 + r] * ndst[row0 + r], bw, bb);
    for (int k = 0; k < F_IN; ++k) {
        const float w = w01[k * WIDTH + tid];
#pragma unroll
        for (int r = 0; r < 8; ++r) acc[r] = fmaf(a_t[r][k], w, acc[r]);
    }
#pragma unroll
    for (int r = 0; r < 8; ++r)
        x_t[r][tid] = fmaxf(acc[r], 0.0f);
    __syncthreads();
    const int c2 = tid & 63;
    const int rb = tid >> 6;
    float acc2[4] = {0.f, 0.f, 0.f, 0.f};
    for (int k = 0; k < WIDTH; ++k) {
        const float w = W2[k * F_OUT + c2];
#pragma unroll
        for (int j = 0; j < 4; ++j) acc2[j] = fmaf(x_t[rb + 2 * j][k], w, acc2[j]);
    }
#pragma unroll
    for (int j = 0; j < 4; ++j)
        hs2h[(size_t)(row0 + rb + 2 * j) * F_OUT + c2] = f2bf(acc2[j]);
}

// K9: agg2[n] = sum_in-edges hs2[src]*w
// 4 waves/block, wave-private staging, 2 halves x 4-edge unroll (8 edges/iter).
__global__ __launch_bounds__(256) void k_gather2(const int* __restrict__ rowp,
                                                 const int2* __restrict__ csr,
                                                 const unsigned* __restrict__ hs2u,
                                                 float2* __restrict__ agg2f2) {
    __shared__ int2 sb[4][64];
    const int wid = threadIdx.x >> 6;
    const int lane = threadIdx.x & 63;
    const int n = blockIdx.x * 4 + wid;
    const int c = lane & 31;
    const int h = lane >> 5;
    int2* my = sb[wid];
    const int start = rowp[n], end = rowp[n + 1];
    float2 acc = {0.f, 0.f};
    for (int base = start; base < end; base += 64) {
        const int m = min(64, end - base);
        my[lane] = (lane < m) ? csr[base + lane] : make_int2(0, 0);
        const int mr = (m + 7) & ~7;
        for (int j = 0; j < mr; j += 8) {
#pragma unroll
            for (int k = 0; k < 4; ++k) {
                int2 sw = my[j + 2 * k + h];
                unsigned a = hs2u[(size_t)sw.x * 32 + c];
                float w = __int_as_float(sw.y);
                acc.x = fmaf(bflo(a), w, acc.x);
                acc.y = fmaf(bfhi(a), w, acc.y);
            }
        }
    }
    acc.x += __shfl_xor(acc.x, 32);
    acc.y += __shfl_xor(acc.y, 32);
    if (lane < 32) agg2f2[(size_t)n * 32 + lane] = acc;
}

// K10: per-graph mean pooling via sorted-gid segments
__global__ __launch_bounds__(64) void k_pool(const float* __restrict__ agg2,
                                             const float* __restrict__ ndst,
                                             const float* __restrict__ b2,
                                             const int* __restrict__ gid,
                                             float* __restrict__ out) {
    const int g = blockIdx.x;
    const int t = threadIdx.x;
    int lo = 0, hi = N_NODES;
    while (lo < hi) { int mid = (lo + hi) >> 1; if (gid[mid] < g) lo = mid + 1; else hi = mid; }
    const int start = lo;
    hi = N_NODES;
    while (lo < hi) { int mid = (lo + hi) >> 1; if (gid[mid] < g + 1) lo = mid + 1; else hi = mid; }
    const int end = lo;
    float sum = 0.0f;
    for (int n = start; n < end; ++n)
        sum = fmaf(agg2[n * F_OUT + t], ndst[n], sum);
    out[g * F_OUT + t] = (end > start) ? (sum / (float)(end - start) + b2[t]) : 0.0f;
}

extern "C" void kernel_launch(void* const* d_in, const int* in_sizes, int n_in,
                              void* d_out, int out_size, void* d_ws, size_t ws_size,
                              hipStream_t stream) {
    const float* af  = (const float*)d_in[0];
    const float* bl  = (const float*)d_in[1];
    const int*   src = (const int*)d_in[2];
    const int*   dst = (const int*)d_in[3];
    const int*   gid = (const int*)d_in[4];
    const float* W0  = (const float*)d_in[5];
    const float* b0  = (const float*)d_in[6];
    const float* W1  = (const float*)d_in[7];
    const float* b1  = (const float*)d_in[8];
    const float* W2  = (const float*)d_in[9];
    const float* b2  = (const float*)d_in[10];
    float* out = (float*)d_out;
    float* ws  = (float*)d_ws;

    int*            rowp   = (int*)(ws + ROWP);
    float*          S      = ws + SVAL;
    float*          nsrc   = ws + NSRC;
    float*          ndst   = ws + NDST;
    int*            bsum   = (int*)(ws + BSUM);
    unsigned char*  rank8  = (unsigned char*)(ws + RNK8);
    unsigned char*  h_dst  = (unsigned char*)(ws + HD);
    unsigned char*  h_src  = (unsigned char*)(ws + HSR);
    unsigned char*  basep  = (unsigned char*)(ws + BASEP);
    int2*           csr    = (int2*)(ws + CSR);
    unsigned*       xb     = (unsigned*)(ws + XB);
    float*          w01    = ws + W01;
    float*          bw1    = ws + BW1;
    float*          g      = ws + GAGG;
    unsigned*       hs2u   = (unsigned*)(ws + HS2);
    unsigned short* hs2h   = (unsigned short*)(ws + HS2);
    float*          agg2   = ws + AGG2;

    const int EB = (N_EDGES + 255) / 256;
    k_hist<<<2 * NBLK_E, 256, 0, stream>>>(src, dst, h_dst, h_src, rank8);
    k_packX<<<(N_NODES * XPITCH) / 256, 256, 0, stream>>>(af, xb);
    k_reduceScan<<<NBLK_SCAN, 256, 0, stream>>>(h_dst, h_src, basep, rowp, bsum, nsrc, ndst);
    k_scanB<<<1, 256, 0, stream>>>(bsum);
    k_scanC<<<NBLK_SCAN, 256, 0, stream>>>(rowp, bsum);
    k_fill<<<EB, 256, 0, stream>>>(bl, src, dst, rank8, basep, rowp, nsrc, csr);
    k_w01<<<F_IN + 1, 128, 0, stream>>>(W0, W1, b0, w01, bw1);
    k_gatherG<<<N_NODES / 4, 256, 0, stream>>>(rowp, csr, xb, (float2*)g, S);
    k_layer1<<<N_NODES / 8, 128, 0, stream>>>(g, S, ndst, w01, bw1, b1, W2, hs2h);
    k_gather2<<<N_NODES / 4, 256, 0, stream>>>(rowp, csr, hs2u, (float2*)agg2);
    k_pool<<<N_GRAPHS, 64, 0, stream>>>(agg2, ndst, b2, gid, out);
}

// Round 9
// 317.704 us; speedup vs baseline: 1.3865x; 1.1231x over previous
//
#include <hip/hip_runtime.h>
#include <hip/hip_fp16.h>

#define N_NODES  50000
#define N_EDGES  1600000
#define N_GRAPHS 1000
#define F_IN     92
#define WIDTH    128
#define F_OUT    64
#define NBLK_SCAN 196        // ceil(50000/256)
#define CHUNK    16384       // edges per histogram chunk (2^14)
#define NBLK_E   98          // ceil(N_EDGES/CHUNK)
#define HPB      25024       // nibble-hist row pitch BYTES
#define HWRD     6256        // HPB/4 u32 words
#define BPITCH   50048       // basep row pitch BYTES (u8 per node)
#define XPITCH   48          // u32 per packed-X row (96 bf16, rows 192B)

// ---- workspace layout (4-byte word offsets) ----
static const size_t ROWP  = 50000;     // i32[50001]
static const size_t SVAL  = 100004;    // f32[50000]
static const size_t NSRC  = 150004;    // f32[50000]
static const size_t NDST  = 200004;    // f32[50000]
static const size_t BSUM  = 250004;    // i32[256]
static const size_t RNK8  = 250260;    // u8[1.6M]
static const size_t HD    = 650260;    // u8[98][25024] dst nibble hist
static const size_t HSR   = 1263348;   // u8[98][25024] src nibble hist
static const size_t BASEP = 1876436;   // u8[98][50048]
static const size_t CSR   = 3102612;   // u32[1.6M] (u16 src | f16 w << 16)
static const size_t XB    = 6302612;   // u32[50000*48] bf16x2 features
static const size_t W01   = 8702612;   // f32[92*128]
static const size_t BW1   = 8714388;   // f32[128]
static const size_t GAGG  = 8714516;   // f32[50000*96]
static const size_t HS2   = 13514516;  // u32[50000*32] bf16x2 x@W2
static const size_t AGG2  = GAGG;      // aliases GAGG (dead after layer1)
static const size_t W01P  = 15114516;  // u32[6144]  fp16-packed W01 B-frags
static const size_t W2P   = 15120660;  // u32[4096]  fp16-packed W2 B-frags
// total = 15,124,756 words = 60.5 MB

typedef __attribute__((ext_vector_type(8))) _Float16 half8v;
typedef __attribute__((ext_vector_type(4))) float f32x4;

__device__ inline unsigned short f2bf(float f) {
    unsigned u = __float_as_uint(f);
    return (unsigned short)((u + 0x7fff + ((u >> 16) & 1)) >> 16);  // RN
}
__device__ inline float bflo(unsigned u) { return __uint_as_float(u << 16); }
__device__ inline float bfhi(unsigned u) { return __uint_as_float(u & 0xffff0000u); }
__device__ inline unsigned short f2h(float f) {
    return __half_as_ushort(__float2half(f));
}
__device__ inline float csr_w(unsigned v) {
    return __half2float(__ushort_as_half((unsigned short)(v >> 16)));
}

// K1: per-chunk LDS NIBBLE histograms. blocks [0,98): dst (+rank); [98,196): src.
__global__ __launch_bounds__(256) void k_hist(const int* __restrict__ src,
                                              const int* __restrict__ dst,
                                              unsigned char* __restrict__ h_dst,
                                              unsigned char* __restrict__ h_src,
                                              unsigned char* __restrict__ rank8) {
    __shared__ unsigned sh[HWRD];
    const bool is_dst = blockIdx.x < NBLK_E;
    const int b = is_dst ? blockIdx.x : blockIdx.x - NBLK_E;
    const int e0 = b * CHUNK;
    const int ecnt = min(CHUNK, N_EDGES - e0);
    for (int i = threadIdx.x; i < HWRD; i += 256) sh[i] = 0;
    __syncthreads();
    const int* __restrict__ idx = is_dst ? dst : src;
    for (int i = threadIdx.x; i < ecnt; i += 256) {
        int v = idx[e0 + i];
        unsigned sh_amt = (v & 7) * 4;
        unsigned old = atomicAdd(&sh[v >> 3], 1u << sh_amt);
        if (is_dst) rank8[e0 + i] = (unsigned char)((old >> sh_amt) & 0xfu);
    }
    __syncthreads();
    unsigned* out = (unsigned*)((is_dst ? h_dst : h_src) + (size_t)b * HPB);
    for (int i = threadIdx.x; i < HWRD; i += 256) out[i] = sh[i];
}

// K2: pack atom_features f32[50000][92] -> bf16x2 u32[50000][48]
__global__ void k_packX(const float* __restrict__ af, unsigned* __restrict__ xb) {
    int idx = blockIdx.x * blockDim.x + threadIdx.x;
    if (idx >= N_NODES * XPITCH) return;
    int n = idx / XPITCH, c = idx - n * XPITCH;
    unsigned v = 0;
    if (c < 46) {
        const float* p = af + (size_t)n * F_IN + 2 * c;
        v = (unsigned)f2bf(p[0]) | ((unsigned)f2bf(p[1]) << 16);
    }
    xb[idx] = v;
}

// K3: column reduce over chunks + fused block-local scan.
__global__ __launch_bounds__(256) void k_reduceScan(const unsigned char* __restrict__ h_dst,
                                                    const unsigned char* __restrict__ h_src,
                                                    unsigned char* __restrict__ basep,
                                                    int* __restrict__ rowp,
                                                    int* __restrict__ bsum,
                                                    float* __restrict__ nsrc,
                                                    float* __restrict__ ndst) {
    __shared__ int sd[256];
    const int t = threadIdx.x;
    const int n = blockIdx.x * 256 + t;
    const bool valid = n < N_NODES;
    unsigned run = 0;
    if (valid) {
        const int byte = n >> 1;
        const int shn = (n & 1) * 4;
        for (int b = 0; b < NBLK_E; ++b) {
            unsigned v = (h_dst[(size_t)b * HPB + byte] >> shn) & 0xfu;
            basep[(size_t)b * BPITCH + n] = (unsigned char)run;
            run += v;
        }
        ndst[n] = rsqrtf((float)max(run, 1u));
        unsigned so = 0;
        for (int b = 0; b < NBLK_E; ++b)
            so += (h_src[(size_t)b * HPB + byte] >> shn) & 0xfu;
        nsrc[n] = rsqrtf((float)max(so, 1u));
    }
    int v = valid ? (int)run : 0;
    sd[t] = v;
    __syncthreads();
    for (int off = 1; off < 256; off <<= 1) {
        int add = (t >= off) ? sd[t - off] : 0;
        __syncthreads();
        sd[t] += add;
        __syncthreads();
    }
    if (valid) rowp[n] = sd[t] - v;
    if (t == 255) bsum[blockIdx.x] = sd[255];
}

// K4b: exclusive scan of block sums  [1 block]
__global__ __launch_bounds__(256) void k_scanB(int* __restrict__ bsum) {
    __shared__ int sd[256];
    const int t = threadIdx.x;
    int v = (t < NBLK_SCAN) ? bsum[t] : 0;
    sd[t] = v;
    __syncthreads();
    for (int off = 1; off < 256; off <<= 1) {
        int add = (t >= off) ? sd[t - off] : 0;
        __syncthreads();
        sd[t] += add;
        __syncthreads();
    }
    if (t < NBLK_SCAN) bsum[t] = sd[t] - v;
}

// K4c: finalize rowp
__global__ void k_scanC(int* __restrict__ rowp, const int* __restrict__ bsum) {
    int i = blockIdx.x * blockDim.x + threadIdx.x;
    if (i >= N_NODES) return;
    rowp[i] = rowp[i] + bsum[i >> 8];
    if (i == 0) rowp[N_NODES] = N_EDGES;
}

// K5: fill CSR (zero atomics). 4-byte entry: u16 src | fp16 w<<16; w folds nsrc[src].
__global__ void k_fill(const float* __restrict__ bl,
                       const int* __restrict__ src, const int* __restrict__ dst,
                       const unsigned char* __restrict__ rank8,
                       const unsigned char* __restrict__ basep,
                       const int* __restrict__ rowp,
                       const float* __restrict__ nsrc,
                       unsigned* __restrict__ csr) {
    int e = blockIdx.x * blockDim.x + threadIdx.x;
    if (e >= N_EDGES) return;
    float x = bl[3 * e + 0], y = bl[3 * e + 1], z = bl[3 * e + 2];
    int s = src[e], d = dst[e];
    float w = expf(-(x * x + y * y + z * z) * (1.0f / 64.0f)) * nsrc[s];
    int b = e >> 14;   // CHUNK = 16384
    int p = rowp[d] + (int)basep[(size_t)b * BPITCH + d] + (int)rank8[e];
    csr[p] = (unsigned)s | ((unsigned)f2h(w) << 16);
}

// K6: W01 = W0 @ W1 [92x128] f32; block 92 computes bW1 = b0 @ W1
__global__ __launch_bounds__(128) void k_w01(const float* __restrict__ W0,
                                             const float* __restrict__ W1,
                                             const float* __restrict__ b0,
                                             float* __restrict__ w01,
                                             float* __restrict__ bw1) {
    const int t = threadIdx.x;
    const int k = blockIdx.x;
    float acc = 0.0f;
    if (k < F_IN) {
        for (int j = 0; j < WIDTH; ++j)
            acc = fmaf(W0[k * WIDTH + j], W1[j * WIDTH + t], acc);
        w01[k * WIDTH + t] = acc;
    } else {
        for (int j = 0; j < WIDTH; ++j)
            acc = fmaf(b0[j], W1[j * WIDTH + t], acc);
        bw1[t] = acc;
    }
}

// K6b: pack W01 (zero-pad K to 96) and W2 into fp16 B-fragment layout.
// B-frag (16x16x32): lane l holds B[k][n] with n = l&15, k = kb*32 + (l>>4)*8 + j.
// Storage: w01p[((t*3+kb)*64+lane)*4+q] = fp16x2 (j=2q, j=2q+1);  8 n-tiles x 3 kb.
//          w2p [((t*4+kb)*64+lane)*4+q];  4 n-tiles x 4 kb.
__global__ __launch_bounds__(256) void k_prepW(const float* __restrict__ w01,
                                               const float* __restrict__ W2,
                                               unsigned* __restrict__ w01p,
                                               unsigned* __restrict__ w2p) {
    int idx = blockIdx.x * 256 + threadIdx.x;
    if (idx < 6144) {
        int q = idx & 3, lane = (idx >> 2) & 63;
        int rest = idx >> 8;              // t*3+kb
        int kb = rest % 3, t = rest / 3;
        int k = kb * 32 + ((lane >> 4) * 8) + 2 * q;
        int n = t * 16 + (lane & 15);
        float lo = (k < F_IN) ? w01[k * WIDTH + n] : 0.f;
        float hi = (k + 1 < F_IN) ? w01[(k + 1) * WIDTH + n] : 0.f;
        w01p[idx] = (unsigned)f2h(lo) | ((unsigned)f2h(hi) << 16);
    } else if (idx < 10240) {
        int i2 = idx - 6144;
        int q = i2 & 3, lane = (i2 >> 2) & 63;
        int rest = i2 >> 8;               // t*4+kb
        int kb = rest & 3, t = rest >> 2;
        int k = kb * 32 + ((lane >> 4) * 8) + 2 * q;
        int n = t * 16 + (lane & 15);
        float lo = W2[k * F_OUT + n];
        float hi = W2[(k + 1) * F_OUT + n];
        w2p[i2] = (unsigned)f2h(lo) | ((unsigned)f2h(hi) << 16);
    }
}

// K7: G[n] = sum_in-edges X_bf16[src]*w ; S[n] = sum w
// 4 waves/block, wave-private LDS staging, 4-edge unroll.
__global__ __launch_bounds__(256) void k_gatherG(const int* __restrict__ rowp,
                                                 const unsigned* __restrict__ csr,
                                                 const unsigned* __restrict__ xb,
                                                 float2* __restrict__ gf2,
                                                 float* __restrict__ S) {
    __shared__ unsigned sb[4][64];
    const int wid = threadIdx.x >> 6;
    const int lane = threadIdx.x & 63;
    const int n = blockIdx.x * 4 + wid;
    const int tc = min(lane, XPITCH - 1);
    unsigned* my = sb[wid];
    const int start = rowp[n], end = rowp[n + 1];
    float2 acc = {0.f, 0.f};
    float ssum = 0.f;
    for (int base = start; base < end; base += 64) {
        const int m = min(64, end - base);
        my[lane] = (lane < m) ? csr[base + lane] : 0u;
        const int mr = (m + 3) & ~3;
        for (int j = 0; j < mr; j += 4) {
            unsigned e0 = my[j], e1 = my[j + 1], e2 = my[j + 2], e3 = my[j + 3];
            unsigned a0 = xb[(size_t)(e0 & 0xFFFFu) * XPITCH + tc];
            unsigned a1 = xb[(size_t)(e1 & 0xFFFFu) * XPITCH + tc];
            unsigned a2 = xb[(size_t)(e2 & 0xFFFFu) * XPITCH + tc];
            unsigned a3 = xb[(size_t)(e3 & 0xFFFFu) * XPITCH + tc];
            float w0 = csr_w(e0), w1 = csr_w(e1), w2 = csr_w(e2), w3 = csr_w(e3);
            acc.x = fmaf(bflo(a0), w0, acc.x);
            acc.y = fmaf(bfhi(a0), w0, acc.y);
            acc.x = fmaf(bflo(a1), w1, acc.x);
            acc.y = fmaf(bfhi(a1), w1, acc.y);
            acc.x = fmaf(bflo(a2), w2, acc.x);
            acc.y = fmaf(bfhi(a2), w2, acc.y);
            acc.x = fmaf(bflo(a3), w3, acc.x);
            acc.y = fmaf(bfhi(a3), w3, acc.y);
            ssum += (w0 + w1) + (w2 + w3);
        }
    }
    if (lane < XPITCH) gf2[(size_t)n * XPITCH + lane] = acc;
    else if (lane == 63) S[n] = ssum;
}

// K8: MFMA layer1. Per wave: 16 rows.
// GEMM1: x[16x96]@W01[96x128] (+ S*bW1 + b1, relu) -> GEMM2: x2[16x128]@W2[128x64].
// A-frag: lane l holds A[m][k], m = l&15, k = (l>>4)*8 + j.
// C/D:    lane l holds C[m][n], n = l&15, m = (l>>4)*4 + r  [HW-verified].
__global__ __launch_bounds__(256) void k_layer1(const float* __restrict__ g,
                                                const float* __restrict__ S,
                                                const float* __restrict__ ndst,
                                                const unsigned* __restrict__ w01p,
                                                const unsigned* __restrict__ w2p,
                                                const float* __restrict__ bw1,
                                                const float* __restrict__ b1,
                                                unsigned short* __restrict__ hs2h) {
    __shared__ unsigned short x2[4][16][136];   // pad 136: 272B row stride, 16B aligned
    __shared__ float svs[4][16];
    const int wid = threadIdx.x >> 6, lane = threadIdx.x & 63;
    const int row0 = blockIdx.x * 64 + wid * 16;
    const int mn = lane & 15;     // A-row (frag build) / C-col (epilogue)
    const int kq = lane >> 4;     // 0..3
    if (lane < 16) {
        int r = row0 + lane;
        svs[wid][lane] = (r < N_NODES) ? S[r] * ndst[r] : 0.f;
    }
    const float nd = ndst[min(row0 + mn, N_NODES - 1)];
    const float* grow = g + (size_t)(row0 + mn) * 96;   // rows >= N read allocated ws
    half8v a1[3];
#pragma unroll
    for (int kb = 0; kb < 3; ++kb) {
        const float4 p0 = *(const float4*)(grow + kb * 32 + kq * 8);
        const float4 p1 = *(const float4*)(grow + kb * 32 + kq * 8 + 4);
        a1[kb][0] = (_Float16)(p0.x * nd); a1[kb][1] = (_Float16)(p0.y * nd);
        a1[kb][2] = (_Float16)(p0.z * nd); a1[kb][3] = (_Float16)(p0.w * nd);
        a1[kb][4] = (_Float16)(p1.x * nd); a1[kb][5] = (_Float16)(p1.y * nd);
        a1[kb][6] = (_Float16)(p1.z * nd); a1[kb][7] = (_Float16)(p1.w * nd);
    }
    for (int t = 0; t < 8; ++t) {
        const float bwv = bw1[t * 16 + mn];
        const float b1v = b1[t * 16 + mn];
        f32x4 acc = {0.f, 0.f, 0.f, 0.f};
        const unsigned* wp = w01p + ((size_t)t * 3 * 64 + lane) * 4;
#pragma unroll
        for (int kb = 0; kb < 3; ++kb) {
            half8v bf = *(const half8v*)(wp + (size_t)kb * 256);
            acc = __builtin_amdgcn_mfma_f32_16x16x32_f16(a1[kb], bf, acc, 0, 0, 0);
        }
#pragma unroll
        for (int r = 0; r < 4; ++r) {
            float v = acc[r] + svs[wid][kq * 4 + r] * bwv + b1v;
            x2[wid][kq * 4 + r][t * 16 + mn] = f2h(fmaxf(v, 0.f));
        }
    }
    // same-wave LDS write->read: ordered by lgkmcnt, no barrier needed
    half8v a2[4];
#pragma unroll
    for (int kb = 0; kb < 4; ++kb)
        a2[kb] = *(const half8v*)&x2[wid][mn][kb * 32 + kq * 8];
    for (int t2 = 0; t2 < 4; ++t2) {
        f32x4 acc = {0.f, 0.f, 0.f, 0.f};
        const unsigned* wp = w2p + ((size_t)t2 * 4 * 64 + lane) * 4;
#pragma unroll
        for (int kb = 0; kb < 4; ++kb) {
            half8v bf = *(const half8v*)(wp + (size_t)kb * 256);
            acc = __builtin_amdgcn_mfma_f32_16x16x32_f16(a2[kb], bf, acc, 0, 0, 0);
        }
#pragma unroll
        for (int r = 0; r < 4; ++r) {
            int row = row0 + kq * 4 + r;
            if (row < N_NODES)
                hs2h[(size_t)row * 64 + t2 * 16 + mn] = f2bf(acc[r]);
        }
    }
}

// K9: agg2[n] = sum_in-edges hs2[src]*w  (4 waves/block, 8 edges/iter)
__global__ __launch_bounds__(256) void k_gather2(const int* __restrict__ rowp,
                                                 const unsigned* __restrict__ csr,
                                                 const unsigned* __restrict__ hs2u,
                                                 float2* __restrict__ agg2f2) {
    __shared__ unsigned sb[4][64];
    const int wid = threadIdx.x >> 6;
    const int lane = threadIdx.x & 63;
    const int n = blockIdx.x * 4 + wid;
    const int c = lane & 31;
    const int h = lane >> 5;
    unsigned* my = sb[wid];
    const int start = rowp[n], end = rowp[n + 1];
    float2 acc = {0.f, 0.f};
    for (int base = start; base < end; base += 64) {
        const int m = min(64, end - base);
        my[lane] = (lane < m) ? csr[base + lane] : 0u;
        const int mr = (m + 7) & ~7;
        for (int j = 0; j < mr; j += 8) {
#pragma unroll
            for (int k = 0; k < 4; ++k) {
                unsigned sw = my[j + 2 * k + h];
                unsigned a = hs2u[(size_t)(sw & 0xFFFFu) * 32 + c];
                float w = csr_w(sw);
                acc.x = fmaf(bflo(a), w, acc.x);
                acc.y = fmaf(bfhi(a), w, acc.y);
            }
        }
    }
    acc.x += __shfl_xor(acc.x, 32);
    acc.y += __shfl_xor(acc.y, 32);
    if (lane < 32) agg2f2[(size_t)n * 32 + lane] = acc;
}

// K10: per-graph mean pooling via sorted-gid segments
__global__ __launch_bounds__(64) void k_pool(const float* __restrict__ agg2,
                                             const float* __restrict__ ndst,
                                             const float* __restrict__ b2,
                                             const int* __restrict__ gid,
                                             float* __restrict__ out) {
    const int g = blockIdx.x;
    const int t = threadIdx.x;
    int lo = 0, hi = N_NODES;
    while (lo < hi) { int mid = (lo + hi) >> 1; if (gid[mid] < g) lo = mid + 1; else hi = mid; }
    const int start = lo;
    hi = N_NODES;
    while (lo < hi) { int mid = (lo + hi) >> 1; if (gid[mid] < g + 1) lo = mid + 1; else hi = mid; }
    const int end = lo;
    float sum = 0.0f;
    for (int n = start; n < end; ++n)
        sum = fmaf(agg2[n * F_OUT + t], ndst[n], sum);
    out[g * F_OUT + t] = (end > start) ? (sum / (float)(end - start) + b2[t]) : 0.0f;
}

extern "C" void kernel_launch(void* const* d_in, const int* in_sizes, int n_in,
                              void* d_out, int out_size, void* d_ws, size_t ws_size,
                              hipStream_t stream) {
    const float* af  = (const float*)d_in[0];
    const float* bl  = (const float*)d_in[1];
    const int*   src = (const int*)d_in[2];
    const int*   dst = (const int*)d_in[3];
    const int*   gid = (const int*)d_in[4];
    const float* W0  = (const float*)d_in[5];
    const float* b0  = (const float*)d_in[6];
    const float* W1  = (const float*)d_in[7];
    const float* b1  = (const float*)d_in[8];
    const float* W2  = (const float*)d_in[9];
    const float* b2  = (const float*)d_in[10];
    float* out = (float*)d_out;
    float* ws  = (float*)d_ws;

    int*            rowp   = (int*)(ws + ROWP);
    float*          S      = ws + SVAL;
    float*          nsrc   = ws + NSRC;
    float*          ndst   = ws + NDST;
    int*            bsum   = (int*)(ws + BSUM);
    unsigned char*  rank8  = (unsigned char*)(ws + RNK8);
    unsigned char*  h_dst  = (unsigned char*)(ws + HD);
    unsigned char*  h_src  = (unsigned char*)(ws + HSR);
    unsigned char*  basep  = (unsigned char*)(ws + BASEP);
    unsigned*       csr    = (unsigned*)(ws + CSR);
    unsigned*       xb     = (unsigned*)(ws + XB);
    float*          w01    = ws + W01;
    float*          bw1    = ws + BW1;
    float*          g      = ws + GAGG;
    unsigned*       hs2u   = (unsigned*)(ws + HS2);
    unsigned short* hs2h   = (unsigned short*)(ws + HS2);
    float*          agg2   = ws + AGG2;
    unsigned*       w01p   = (unsigned*)(ws + W01P);
    unsigned*       w2p    = (unsigned*)(ws + W2P);

    const int EB = (N_EDGES + 255) / 256;
    k_hist<<<2 * NBLK_E, 256, 0, stream>>>(src, dst, h_dst, h_src, rank8);
    k_packX<<<(N_NODES * XPITCH) / 256, 256, 0, stream>>>(af, xb);
    k_reduceScan<<<NBLK_SCAN, 256, 0, stream>>>(h_dst, h_src, basep, rowp, bsum, nsrc, ndst);
    k_scanB<<<1, 256, 0, stream>>>(bsum);
    k_scanC<<<NBLK_SCAN, 256, 0, stream>>>(rowp, bsum);
    k_fill<<<EB, 256, 0, stream>>>(bl, src, dst, rank8, basep, rowp, nsrc, csr);
    k_w01<<<F_IN + 1, 128, 0, stream>>>(W0, W1, b0, w01, bw1);
    k_prepW<<<40, 256, 0, stream>>>(w01, W2, w01p, w2p);
    k_gatherG<<<N_NODES / 4, 256, 0, stream>>>(rowp, csr, xb, (float2*)g, S);
    k_layer1<<<(N_NODES + 63) / 64, 256, 0, stream>>>(g, S, ndst, w01p, w2p, bw1, b1, hs2h);
    k_gather2<<<N_NODES / 4, 256, 0, stream>>>(rowp, csr, hs2u, (float2*)agg2);
    k_pool<<<N_GRAPHS, 64, 0, stream>>>(agg2, ndst, b2, gid, out);
}

// Round 10
// 291.298 us; speedup vs baseline: 1.5122x; 1.0906x over previous
//
#include <hip/hip_runtime.h>
#include <hip/hip_fp16.h>

#define N_NODES  50000
#define N_EDGES  1600000
#define N_GRAPHS 1000
#define F_IN     92
#define WIDTH    128
#define F_OUT    64
#define CHUNK    16384       // edges per src-hist chunk
#define NBLK_E   98          // ceil(N_EDGES/CHUNK)
#define HPB      25024       // nibble-hist row pitch BYTES
#define HWRD     6256        // HPB/4 u32 words
#define XPITCH   48          // u32 per packed-X row (96 bf16, 192B)
#define BKT      196         // dst buckets (256 nodes each; 196*256 = 50176)
#define CAP      9216        // staging slots per bucket (avg 8163, +11 sigma)
#define BINCHUNK 4096
#define NBIN     391         // ceil(N_EDGES/BINCHUNK)

// ---- workspace layout (4-byte word offsets) ----
static const size_t CURS  = 0;         // u32[256] bucket cursors
static const size_t CSRB  = 256;       // i32[256] bucket CSR bases
static const size_t NSRC  = 520;       // f32[50000]
static const size_t NDST  = 50520;     // f32[50000]
static const size_t SVAL  = 100520;    // f32[50000]
static const size_t ROWP  = 150520;    // i32[50001] (pad 200528)
static const size_t HSR   = 200528;    // u8[98][25024] src nibble hist
static const size_t SGW   = 813616;    // u32[196*9216] staged (src16|w16)
static const size_t SGB   = 2619952;   // u8 [196*9216] staged dst-low-byte
static const size_t CSR   = 3071536;   // u32[1.6M] final sorted CSR
static const size_t XB    = 4671536;   // u32[50000*48] bf16x2 features
static const size_t W01   = 7071536;   // f32[92*128]
static const size_t BW1   = 7083312;   // f32[128]
static const size_t W01P  = 7083440;   // u32[6144] fp16 W01 B-frags
static const size_t W2P   = 7089584;   // u32[4096] fp16 W2 B-frags
static const size_t GAGG  = 7093680;   // f32[50000*96]
static const size_t HS2   = 11893680;  // u32[50000*32]
static const size_t AGG2  = GAGG;      // aliases GAGG (dead after layer1)
// total = 13,493,680 words = 54.0 MB

typedef __attribute__((ext_vector_type(8))) _Float16 half8v;
typedef __attribute__((ext_vector_type(4))) float f32x4;

__device__ inline unsigned short f2bf(float f) {
    unsigned u = __float_as_uint(f);
    return (unsigned short)((u + 0x7fff + ((u >> 16) & 1)) >> 16);  // RN
}
__device__ inline float bflo(unsigned u) { return __uint_as_float(u << 16); }
__device__ inline float bfhi(unsigned u) { return __uint_as_float(u & 0xffff0000u); }
__device__ inline unsigned short f2h(float f) {
    return __half_as_ushort(__float2half(f));
}
__device__ inline float csr_w(unsigned v) {
    return __half2float(__ushort_as_half((unsigned short)(v >> 16)));
}

// K0: init bucket cursors to fixed per-bucket staging bases
__global__ void k_init(unsigned* __restrict__ cursor) {
    cursor[threadIdx.x] = (unsigned)threadIdx.x * CAP;
}

// K1: src-only nibble histogram (for out-degree / nsrc)
__global__ __launch_bounds__(256) void k_srcHist(const int* __restrict__ src,
                                                 unsigned char* __restrict__ h_src) {
    __shared__ unsigned sh[HWRD];
    const int e0 = blockIdx.x * CHUNK;
    const int ecnt = min(CHUNK, N_EDGES - e0);
    for (int i = threadIdx.x; i < HWRD; i += 256) sh[i] = 0;
    __syncthreads();
    for (int i = threadIdx.x; i < ecnt; i += 256) {
        int v = src[e0 + i];
        atomicAdd(&sh[v >> 3], 1u << ((v & 7) * 4));
    }
    __syncthreads();
    unsigned* out = (unsigned*)(h_src + (size_t)blockIdx.x * HPB);
    for (int i = threadIdx.x; i < HWRD; i += 256) out[i] = sh[i];
}

// K2: nsrc = rsqrt(max(out_deg,1)) from src nibbles
__global__ __launch_bounds__(256) void k_nsrc(const unsigned char* __restrict__ h_src,
                                              float* __restrict__ nsrc) {
    int n = blockIdx.x * 256 + threadIdx.x;
    if (n >= N_NODES) return;
    const int byte = n >> 1, shn = (n & 1) * 4;
    unsigned so = 0;
    for (int b = 0; b < NBLK_E; ++b)
        so += (h_src[(size_t)b * HPB + byte] >> shn) & 0xfu;
    nsrc[n] = rsqrtf((float)max(so, 1u));
}

// K3: pack atom_features f32[50000][92] -> bf16x2 u32[50000][48]
__global__ void k_packX(const float* __restrict__ af, unsigned* __restrict__ xb) {
    int idx = blockIdx.x * blockDim.x + threadIdx.x;
    if (idx >= N_NODES * XPITCH) return;
    int n = idx / XPITCH, c = idx - n * XPITCH;
    unsigned v = 0;
    if (c < 46) {
        const float* p = af + (size_t)n * F_IN + 2 * c;
        v = (unsigned)f2bf(p[0]) | ((unsigned)f2bf(p[1]) << 16);
    }
    xb[idx] = v;
}

// K4: bin pass — compute w, group per-block by 256-node dst-bucket (LDS rank),
// reserve global staging slots (1 atomic per block-bucket), write block-contiguous
// runs. Fixes k_fill's 8x cross-XCD partial-line writeback.
__global__ __launch_bounds__(256) void k_bin(const float* __restrict__ bl,
                                             const int* __restrict__ src,
                                             const int* __restrict__ dst,
                                             const float* __restrict__ nsrc,
                                             unsigned* __restrict__ cursor,
                                             unsigned* __restrict__ sgw,
                                             unsigned char* __restrict__ sgb) {
    __shared__ unsigned hcnt[256];
    __shared__ unsigned gbase[256];
    const int t = threadIdx.x;
    const int e0 = blockIdx.x * BINCHUNK;
    hcnt[t] = 0;
    __syncthreads();
    unsigned entry[16], meta[16];
#pragma unroll
    for (int i = 0; i < 16; ++i) {
        int e = e0 + t + i * 256;
        meta[i] = 0xFFFFFFFFu;
        if (e < N_EDGES) {
            float x = bl[3 * e], y = bl[3 * e + 1], z = bl[3 * e + 2];
            int s = src[e], d = dst[e];
            float w = expf(-(x * x + y * y + z * z) * (1.0f / 64.0f)) * nsrc[s];
            entry[i] = (unsigned)s | ((unsigned)f2h(w) << 16);
            int bkt = d >> 8;
            unsigned r = atomicAdd(&hcnt[bkt], 1u);           // rank < 4096, 12 bits
            meta[i] = ((unsigned)bkt << 20) | ((unsigned)(d & 255) << 12) | r;
        }
    }
    __syncthreads();
    if (t < BKT) gbase[t] = hcnt[t] ? atomicAdd(&cursor[t], hcnt[t]) : 0u;
    __syncthreads();
#pragma unroll
    for (int i = 0; i < 16; ++i) {
        if (meta[i] != 0xFFFFFFFFu) {
            unsigned bkt = meta[i] >> 20;
            unsigned slot = gbase[bkt] + (meta[i] & 0xFFFu);
            if (slot < (bkt + 1) * CAP) {                     // impossible-overflow guard
                sgw[slot] = entry[i];
                sgb[slot] = (unsigned char)((meta[i] >> 12) & 0xFFu);
            }
        }
    }
}

// K5: exclusive scan of bucket counts -> bucket CSR bases; rowp[N]=E
__global__ __launch_bounds__(256) void k_bscan(const unsigned* __restrict__ cursor,
                                               int* __restrict__ csrb,
                                               int* __restrict__ rowp) {
    __shared__ int sd[256];
    const int t = threadIdx.x;
    int c = (t < BKT) ? (int)(cursor[t] - (unsigned)t * CAP) : 0;
    sd[t] = c;
    __syncthreads();
    for (int off = 1; off < 256; off <<= 1) {
        int v = (t >= off) ? sd[t - off] : 0;
        __syncthreads();
        sd[t] += v;
        __syncthreads();
    }
    if (t < BKT) csrb[t] = sd[t] - c;
    if (t == 0) rowp[N_NODES] = N_EDGES;
}

// K6: per-bucket LDS counting sort -> final sorted CSR (streaming, single-XCD
// full lines), rowp and ndst for the bucket's 256 nodes.
__global__ __launch_bounds__(256) void k_csr(const unsigned* __restrict__ cursor,
                                             const int* __restrict__ csrb,
                                             const unsigned* __restrict__ sgw,
                                             const unsigned char* __restrict__ sgb,
                                             unsigned* __restrict__ csr,
                                             int* __restrict__ rowp,
                                             float* __restrict__ ndst) {
    __shared__ unsigned se[CAP];          // 36.9 KB
    __shared__ unsigned char sd8[CAP];    // 9.2 KB
    __shared__ unsigned dh[256];
    __shared__ unsigned dcur[256];
    __shared__ int sscan[256];
    const int b = blockIdx.x, t = threadIdx.x;
    const int cnt = (int)(cursor[b] - (unsigned)b * CAP);
    const int base = csrb[b];
    for (int i = t; i < cnt; i += 256) {
        se[i] = sgw[(size_t)b * CAP + i];
        sd8[i] = sgb[(size_t)b * CAP + i];
    }
    dh[t] = 0;
    __syncthreads();
    for (int i = t; i < cnt; i += 256) atomicAdd(&dh[sd8[i]], 1u);
    __syncthreads();
    int v = (int)dh[t];
    sscan[t] = v;
    __syncthreads();
    for (int off = 1; off < 256; off <<= 1) {
        int a = (t >= off) ? sscan[t - off] : 0;
        __syncthreads();
        sscan[t] += a;
        __syncthreads();
    }
    dcur[t] = (unsigned)(sscan[t] - v);
    const int node = b * 256 + t;
    if (node < N_NODES) {
        rowp[node] = base + (sscan[t] - v);
        ndst[node] = rsqrtf((float)max((unsigned)v, 1u));
    }
    __syncthreads();
    for (int i = t; i < cnt; i += 256) {
        unsigned pos = atomicAdd(&dcur[sd8[i]], 1u);
        csr[(size_t)base + pos] = se[i];
    }
}

// K7: W01 = W0 @ W1 [92x128] f32; block 92 computes bW1 = b0 @ W1
__global__ __launch_bounds__(128) void k_w01(const float* __restrict__ W0,
                                             const float* __restrict__ W1,
                                             const float* __restrict__ b0,
                                             float* __restrict__ w01,
                                             float* __restrict__ bw1) {
    const int t = threadIdx.x;
    const int k = blockIdx.x;
    float acc = 0.0f;
    if (k < F_IN) {
        for (int j = 0; j < WIDTH; ++j)
            acc = fmaf(W0[k * WIDTH + j], W1[j * WIDTH + t], acc);
        w01[k * WIDTH + t] = acc;
    } else {
        for (int j = 0; j < WIDTH; ++j)
            acc = fmaf(b0[j], W1[j * WIDTH + t], acc);
        bw1[t] = acc;
    }
}

// K7b: pack W01 (zero-pad K to 96) and W2 into fp16 B-fragment layout.
__global__ __launch_bounds__(256) void k_prepW(const float* __restrict__ w01,
                                               const float* __restrict__ W2,
                                               unsigned* __restrict__ w01p,
                                               unsigned* __restrict__ w2p) {
    int idx = blockIdx.x * 256 + threadIdx.x;
    if (idx < 6144) {
        int q = idx & 3, lane = (idx >> 2) & 63;
        int rest = idx >> 8;              // t*3+kb
        int kb = rest % 3, t = rest / 3;
        int k = kb * 32 + ((lane >> 4) * 8) + 2 * q;
        int n = t * 16 + (lane & 15);
        float lo = (k < F_IN) ? w01[k * WIDTH + n] : 0.f;
        float hi = (k + 1 < F_IN) ? w01[(k + 1) * WIDTH + n] : 0.f;
        w01p[idx] = (unsigned)f2h(lo) | ((unsigned)f2h(hi) << 16);
    } else if (idx < 10240) {
        int i2 = idx - 6144;
        int q = i2 & 3, lane = (i2 >> 2) & 63;
        int rest = i2 >> 8;               // t*4+kb
        int kb = rest & 3, t = rest >> 2;
        int k = kb * 32 + ((lane >> 4) * 8) + 2 * q;
        int n = t * 16 + (lane & 15);
        float lo = W2[k * F_OUT + n];
        float hi = W2[(k + 1) * F_OUT + n];
        w2p[i2] = (unsigned)f2h(lo) | ((unsigned)f2h(hi) << 16);
    }
}

// K8: G[n] = sum_in-edges X_bf16[src]*w ; S[n] = sum w
// 4 waves/block, wave-private LDS staging, 4-edge unroll.
__global__ __launch_bounds__(256) void k_gatherG(const int* __restrict__ rowp,
                                                 const unsigned* __restrict__ csr,
                                                 const unsigned* __restrict__ xb,
                                                 float2* __restrict__ gf2,
                                                 float* __restrict__ S) {
    __shared__ unsigned sb[4][64];
    const int wid = threadIdx.x >> 6;
    const int lane = threadIdx.x & 63;
    const int n = blockIdx.x * 4 + wid;
    const int tc = min(lane, XPITCH - 1);
    unsigned* my = sb[wid];
    const int start = rowp[n], end = rowp[n + 1];
    float2 acc = {0.f, 0.f};
    float ssum = 0.f;
    for (int base = start; base < end; base += 64) {
        const int m = min(64, end - base);
        my[lane] = (lane < m) ? csr[base + lane] : 0u;
        const int mr = (m + 3) & ~3;
        for (int j = 0; j < mr; j += 4) {
            unsigned e0 = my[j], e1 = my[j + 1], e2 = my[j + 2], e3 = my[j + 3];
            unsigned a0 = xb[(size_t)(e0 & 0xFFFFu) * XPITCH + tc];
            unsigned a1 = xb[(size_t)(e1 & 0xFFFFu) * XPITCH + tc];
            unsigned a2 = xb[(size_t)(e2 & 0xFFFFu) * XPITCH + tc];
            unsigned a3 = xb[(size_t)(e3 & 0xFFFFu) * XPITCH + tc];
            float w0 = csr_w(e0), w1 = csr_w(e1), w2 = csr_w(e2), w3 = csr_w(e3);
            acc.x = fmaf(bflo(a0), w0, acc.x);
            acc.y = fmaf(bfhi(a0), w0, acc.y);
            acc.x = fmaf(bflo(a1), w1, acc.x);
            acc.y = fmaf(bfhi(a1), w1, acc.y);
            acc.x = fmaf(bflo(a2), w2, acc.x);
            acc.y = fmaf(bfhi(a2), w2, acc.y);
            acc.x = fmaf(bflo(a3), w3, acc.x);
            acc.y = fmaf(bfhi(a3), w3, acc.y);
            ssum += (w0 + w1) + (w2 + w3);
        }
    }
    if (lane < XPITCH) gf2[(size_t)n * XPITCH + lane] = acc;
    else if (lane == 63) S[n] = ssum;
}

// K9: MFMA layer1 (16 rows/wave): GEMM1 + bias/relu -> GEMM2 -> bf16 hs2
__global__ __launch_bounds__(256) void k_layer1(const float* __restrict__ g,
                                                const float* __restrict__ S,
                                                const float* __restrict__ ndst,
                                                const unsigned* __restrict__ w01p,
                                                const unsigned* __restrict__ w2p,
                                                const float* __restrict__ bw1,
                                                const float* __restrict__ b1,
                                                unsigned short* __restrict__ hs2h) {
    __shared__ unsigned short x2[4][16][136];
    __shared__ float svs[4][16];
    const int wid = threadIdx.x >> 6, lane = threadIdx.x & 63;
    const int row0 = blockIdx.x * 64 + wid * 16;
    const int mn = lane & 15;
    const int kq = lane >> 4;
    if (lane < 16) {
        int r = row0 + lane;
        svs[wid][lane] = (r < N_NODES) ? S[r] * ndst[r] : 0.f;
    }
    const float nd = ndst[min(row0 + mn, N_NODES - 1)];
    const float* grow = g + (size_t)(row0 + mn) * 96;
    half8v a1[3];
#pragma unroll
    for (int kb = 0; kb < 3; ++kb) {
        const float4 p0 = *(const float4*)(grow + kb * 32 + kq * 8);
        const float4 p1 = *(const float4*)(grow + kb * 32 + kq * 8 + 4);
        a1[kb][0] = (_Float16)(p0.x * nd); a1[kb][1] = (_Float16)(p0.y * nd);
        a1[kb][2] = (_Float16)(p0.z * nd); a1[kb][3] = (_Float16)(p0.w * nd);
        a1[kb][4] = (_Float16)(p1.x * nd); a1[kb][5] = (_Float16)(p1.y * nd);
        a1[kb][6] = (_Float16)(p1.z * nd); a1[kb][7] = (_Float16)(p1.w * nd);
    }
    for (int t = 0; t < 8; ++t) {
        const float bwv = bw1[t * 16 + mn];
        const float b1v = b1[t * 16 + mn];
        f32x4 acc = {0.f, 0.f, 0.f, 0.f};
        const unsigned* wp = w01p + ((size_t)t * 3 * 64 + lane) * 4;
#pragma unroll
        for (int kb = 0; kb < 3; ++kb) {
            half8v bf = *(const half8v*)(wp + (size_t)kb * 256);
            acc = __builtin_amdgcn_mfma_f32_16x16x32_f16(a1[kb], bf, acc, 0, 0, 0);
        }
#pragma unroll
        for (int r = 0; r < 4; ++r) {
            float v = acc[r] + svs[wid][kq * 4 + r] * bwv + b1v;
            x2[wid][kq * 4 + r][t * 16 + mn] = f2h(fmaxf(v, 0.f));
        }
    }
    half8v a2[4];
#pragma unroll
    for (int kb = 0; kb < 4; ++kb)
        a2[kb] = *(const half8v*)&x2[wid][mn][kb * 32 + kq * 8];
    for (int t2 = 0; t2 < 4; ++t2) {
        f32x4 acc = {0.f, 0.f, 0.f, 0.f};
        const unsigned* wp = w2p + ((size_t)t2 * 4 * 64 + lane) * 4;
#pragma unroll
        for (int kb = 0; kb < 4; ++kb) {
            half8v bf = *(const half8v*)(wp + (size_t)kb * 256);
            acc = __builtin_amdgcn_mfma_f32_16x16x32_f16(a2[kb], bf, acc, 0, 0, 0);
        }
#pragma unroll
        for (int r = 0; r < 4; ++r) {
            int row = row0 + kq * 4 + r;
            if (row < N_NODES)
                hs2h[(size_t)row * 64 + t2 * 16 + mn] = f2bf(acc[r]);
        }
    }
}

// K10: agg2[n] = sum_in-edges hs2[src]*w  (4 waves/block, 8 edges/iter)
__global__ __launch_bounds__(256) void k_gather2(const int* __restrict__ rowp,
                                                 const unsigned* __restrict__ csr,
                                                 const unsigned* __restrict__ hs2u,
                                                 float2* __restrict__ agg2f2) {
    __shared__ unsigned sb[4][64];
    const int wid = threadIdx.x >> 6;
    const int lane = threadIdx.x & 63;
    const int n = blockIdx.x * 4 + wid;
    const int c = lane & 31;
    const int h = lane >> 5;
    unsigned* my = sb[wid];
    const int start = rowp[n], end = rowp[n + 1];
    float2 acc = {0.f, 0.f};
    for (int base = start; base < end; base += 64) {
        const int m = min(64, end - base);
        my[lane] = (lane < m) ? csr[base + lane] : 0u;
        const int mr = (m + 7) & ~7;
        for (int j = 0; j < mr; j += 8) {
#pragma unroll
            for (int k = 0; k < 4; ++k) {
                unsigned sw = my[j + 2 * k + h];
                unsigned a = hs2u[(size_t)(sw & 0xFFFFu) * 32 + c];
                float w = csr_w(sw);
                acc.x = fmaf(bflo(a), w, acc.x);
                acc.y = fmaf(bfhi(a), w, acc.y);
            }
        }
    }
    acc.x += __shfl_xor(acc.x, 32);
    acc.y += __shfl_xor(acc.y, 32);
    if (lane < 32) agg2f2[(size_t)n * 32 + lane] = acc;
}

// K11: per-graph mean pooling via sorted-gid segments
__global__ __launch_bounds__(64) void k_pool(const float* __restrict__ agg2,
                                             const float* __restrict__ ndst,
                                             const float* __restrict__ b2,
                                             const int* __restrict__ gid,
                                             float* __restrict__ out) {
    const int g = blockIdx.x;
    const int t = threadIdx.x;
    int lo = 0, hi = N_NODES;
    while (lo < hi) { int mid = (lo + hi) >> 1; if (gid[mid] < g) lo = mid + 1; else hi = mid; }
    const int start = lo;
    hi = N_NODES;
    while (lo < hi) { int mid = (lo + hi) >> 1; if (gid[mid] < g + 1) lo = mid + 1; else hi = mid; }
    const int end = lo;
    float sum = 0.0f;
    for (int n = start; n < end; ++n)
        sum = fmaf(agg2[n * F_OUT + t], ndst[n], sum);
    out[g * F_OUT + t] = (end > start) ? (sum / (float)(end - start) + b2[t]) : 0.0f;
}

extern "C" void kernel_launch(void* const* d_in, const int* in_sizes, int n_in,
                              void* d_out, int out_size, void* d_ws, size_t ws_size,
                              hipStream_t stream) {
    const float* af  = (const float*)d_in[0];
    const float* bl  = (const float*)d_in[1];
    const int*   src = (const int*)d_in[2];
    const int*   dst = (const int*)d_in[3];
    const int*   gid = (const int*)d_in[4];
    const float* W0  = (const float*)d_in[5];
    const float* b0  = (const float*)d_in[6];
    const float* W1  = (const float*)d_in[7];
    const float* b1  = (const float*)d_in[8];
    const float* W2  = (const float*)d_in[9];
    const float* b2  = (const float*)d_in[10];
    float* out = (float*)d_out;
    float* ws  = (float*)d_ws;

    unsigned*       cursor = (unsigned*)(ws + CURS);
    int*            csrb   = (int*)(ws + CSRB);
    float*          nsrc   = ws + NSRC;
    float*          ndst   = ws + NDST;
    float*          S      = ws + SVAL;
    int*            rowp   = (int*)(ws + ROWP);
    unsigned char*  h_src  = (unsigned char*)(ws + HSR);
    unsigned*       sgw    = (unsigned*)(ws + SGW);
    unsigned char*  sgb    = (unsigned char*)(ws + SGB);
    unsigned*       csr    = (unsigned*)(ws + CSR);
    unsigned*       xb     = (unsigned*)(ws + XB);
    float*          w01    = ws + W01;
    float*          bw1    = ws + BW1;
    unsigned*       w01p   = (unsigned*)(ws + W01P);
    unsigned*       w2p    = (unsigned*)(ws + W2P);
    float*          g      = ws + GAGG;
    unsigned*       hs2u   = (unsigned*)(ws + HS2);
    unsigned short* hs2h   = (unsigned short*)(ws + HS2);
    float*          agg2   = ws + AGG2;

    k_init<<<1, 256, 0, stream>>>(cursor);
    k_srcHist<<<NBLK_E, 256, 0, stream>>>(src, h_src);
    k_packX<<<(N_NODES * XPITCH) / 256, 256, 0, stream>>>(af, xb);
    k_nsrc<<<BKT, 256, 0, stream>>>(h_src, nsrc);
    k_bin<<<NBIN, 256, 0, stream>>>(bl, src, dst, nsrc, cursor, sgw, sgb);
    k_bscan<<<1, 256, 0, stream>>>(cursor, csrb, rowp);
    k_csr<<<BKT, 256, 0, stream>>>(cursor, csrb, sgw, sgb, csr, rowp, ndst);
    k_w01<<<F_IN + 1, 128, 0, stream>>>(W0, W1, b0, w01, bw1);
    k_prepW<<<40, 256, 0, stream>>>(w01, W2, w01p, w2p);
    k_gatherG<<<N_NODES / 4, 256, 0, stream>>>(rowp, csr, xb, (float2*)g, S);
    k_layer1<<<(N_NODES + 63) / 64, 256, 0, stream>>>(g, S, ndst, w01p, w2p, bw1, b1, hs2h);
    k_gather2<<<N_NODES / 4, 256, 0, stream>>>(rowp, csr, hs2u, (float2*)agg2);
    k_pool<<<N_GRAPHS, 64, 0, stream>>>(agg2, ndst, b2, gid, out);
}

// Round 11
// 283.756 us; speedup vs baseline: 1.5524x; 1.0266x over previous
//
#include <hip/hip_runtime.h>
#include <hip/hip_fp16.h>

#define N_NODES  50000
#define N_EDGES  1600000
#define N_GRAPHS 1000
#define F_IN     92
#define WIDTH    128
#define F_OUT    64
#define CHUNK    16384       // edges per src-hist chunk
#define NBLK_E   98          // ceil(N_EDGES/CHUNK)
#define HPB      25024       // nibble-hist row pitch BYTES
#define HWRD     6256        // HPB/4 u32 words
#define XPITCH   48          // u32 per packed-X row (96 bf16, 192B)
#define BKT      196         // dst buckets (256 nodes each)
#define CAP      9216        // staging slots per bucket
#define BINCHUNK 4096
#define NBIN     391         // ceil(N_EDGES/BINCHUNK)

// ---- workspace layout (4-byte word offsets) ----
static const size_t CURS  = 0;         // u32[256] bucket cursors
static const size_t CSRB  = 256;       // i32[256] bucket CSR bases
static const size_t NSRC  = 520;       // f32[50000]
static const size_t NDST  = 50520;     // f32[50000]
static const size_t ROWP  = 150520;    // i32[50001]
static const size_t HSR   = 200528;    // u8[98][25024] src nibble hist
static const size_t SGW   = 813616;    // u32[196*9216] staged (src16|w16)
static const size_t SGB   = 2619952;   // u8 [196*9216] staged dst-low-byte
static const size_t CSR   = 3071536;   // u32[1.6M] final sorted CSR
static const size_t XB    = 4671536;   // u32[50000*48] bf16x2 features (+unit S col)
static const size_t W01   = 7071536;   // f32[92*128]
static const size_t BW1   = 7083312;   // f32[128]
static const size_t W01P  = 7083440;   // u32[6144] fp16 W01 B-frags
static const size_t W2P   = 7089584;   // u32[4096] fp16 W2 B-frags
static const size_t GAGG  = 7093680;   // f32[50000*96]  (ch 92 = S)
static const size_t HS2   = 11893680;  // u32[50000*32]
static const size_t AGG2  = GAGG;      // aliases GAGG (dead after layer1)
// total = 13,493,680 words = 54.0 MB

typedef __attribute__((ext_vector_type(8))) _Float16 half8v;
typedef __attribute__((ext_vector_type(4))) float f32x4;

__device__ inline unsigned short f2bf(float f) {
    unsigned u = __float_as_uint(f);
    return (unsigned short)((u + 0x7fff + ((u >> 16) & 1)) >> 16);  // RN
}
__device__ inline float bflo(unsigned u) { return __uint_as_float(u << 16); }
__device__ inline float bfhi(unsigned u) { return __uint_as_float(u & 0xffff0000u); }
__device__ inline unsigned short f2h(float f) {
    return __half_as_ushort(__float2half(f));
}
__device__ inline float csr_w(unsigned v) {
    return __half2float(__ushort_as_half((unsigned short)(v >> 16)));
}

// K0: init bucket cursors
__global__ void k_init(unsigned* __restrict__ cursor) {
    cursor[threadIdx.x] = (unsigned)threadIdx.x * CAP;
}

// K1: src-only nibble histogram (out-degree)
__global__ __launch_bounds__(256) void k_srcHist(const int* __restrict__ src,
                                                 unsigned char* __restrict__ h_src) {
    __shared__ unsigned sh[HWRD];
    const int e0 = blockIdx.x * CHUNK;
    const int ecnt = min(CHUNK, N_EDGES - e0);
    for (int i = threadIdx.x; i < HWRD; i += 256) sh[i] = 0;
    __syncthreads();
    for (int i = threadIdx.x; i < ecnt; i += 256) {
        int v = src[e0 + i];
        atomicAdd(&sh[v >> 3], 1u << ((v & 7) * 4));
    }
    __syncthreads();
    unsigned* out = (unsigned*)(h_src + (size_t)blockIdx.x * HPB);
    for (int i = threadIdx.x; i < HWRD; i += 256) out[i] = sh[i];
}

// K2: nsrc = rsqrt(max(out_deg,1))
__global__ __launch_bounds__(256) void k_nsrc(const unsigned char* __restrict__ h_src,
                                              float* __restrict__ nsrc) {
    int n = blockIdx.x * 256 + threadIdx.x;
    if (n >= N_NODES) return;
    const int byte = n >> 1, shn = (n & 1) * 4;
    unsigned so = 0;
    for (int b = 0; b < NBLK_E; ++b)
        so += (h_src[(size_t)b * HPB + byte] >> shn) & 0xfu;
    nsrc[n] = rsqrtf((float)max(so, 1u));
}

// K3: pack features -> bf16x2 u32[50000][48]; col 46 low half = bf16(1.0) (S column)
__global__ void k_packX(const float* __restrict__ af, unsigned* __restrict__ xb) {
    int idx = blockIdx.x * blockDim.x + threadIdx.x;
    if (idx >= N_NODES * XPITCH) return;
    int n = idx / XPITCH, c = idx - n * XPITCH;
    unsigned v = 0;
    if (c < 46) {
        const float* p = af + (size_t)n * F_IN + 2 * c;
        v = (unsigned)f2bf(p[0]) | ((unsigned)f2bf(p[1]) << 16);
    } else if (c == 46) {
        v = 0x3F80u;   // bf16(1.0) in low half -> channel 92 accumulates sum(w)
    }
    xb[idx] = v;
}

// K4: bin pass — per-block bucket grouping, block-contiguous staging writes
__global__ __launch_bounds__(256) void k_bin(const float* __restrict__ bl,
                                             const int* __restrict__ src,
                                             const int* __restrict__ dst,
                                             const float* __restrict__ nsrc,
                                             unsigned* __restrict__ cursor,
                                             unsigned* __restrict__ sgw,
                                             unsigned char* __restrict__ sgb) {
    __shared__ unsigned hcnt[256];
    __shared__ unsigned gbase[256];
    const int t = threadIdx.x;
    const int e0 = blockIdx.x * BINCHUNK;
    hcnt[t] = 0;
    __syncthreads();
    unsigned entry[16], meta[16];
#pragma unroll
    for (int i = 0; i < 16; ++i) {
        int e = e0 + t + i * 256;
        meta[i] = 0xFFFFFFFFu;
        if (e < N_EDGES) {
            float x = bl[3 * e], y = bl[3 * e + 1], z = bl[3 * e + 2];
            int s = src[e], d = dst[e];
            float w = expf(-(x * x + y * y + z * z) * (1.0f / 64.0f)) * nsrc[s];
            entry[i] = (unsigned)s | ((unsigned)f2h(w) << 16);
            int bkt = d >> 8;
            unsigned r = atomicAdd(&hcnt[bkt], 1u);
            meta[i] = ((unsigned)bkt << 20) | ((unsigned)(d & 255) << 12) | r;
        }
    }
    __syncthreads();
    if (t < BKT) gbase[t] = hcnt[t] ? atomicAdd(&cursor[t], hcnt[t]) : 0u;
    __syncthreads();
#pragma unroll
    for (int i = 0; i < 16; ++i) {
        if (meta[i] != 0xFFFFFFFFu) {
            unsigned bkt = meta[i] >> 20;
            unsigned slot = gbase[bkt] + (meta[i] & 0xFFFu);
            if (slot < (bkt + 1) * CAP) {
                sgw[slot] = entry[i];
                sgb[slot] = (unsigned char)((meta[i] >> 12) & 0xFFu);
            }
        }
    }
}

// K5: scan bucket counts -> bucket CSR bases
__global__ __launch_bounds__(256) void k_bscan(const unsigned* __restrict__ cursor,
                                               int* __restrict__ csrb,
                                               int* __restrict__ rowp) {
    __shared__ int sd[256];
    const int t = threadIdx.x;
    int c = (t < BKT) ? (int)(cursor[t] - (unsigned)t * CAP) : 0;
    sd[t] = c;
    __syncthreads();
    for (int off = 1; off < 256; off <<= 1) {
        int v = (t >= off) ? sd[t - off] : 0;
        __syncthreads();
        sd[t] += v;
        __syncthreads();
    }
    if (t < BKT) csrb[t] = sd[t] - c;
    if (t == 0) rowp[N_NODES] = N_EDGES;
}

// K6: per-bucket LDS counting sort -> final CSR + rowp + ndst
__global__ __launch_bounds__(256) void k_csr(const unsigned* __restrict__ cursor,
                                             const int* __restrict__ csrb,
                                             const unsigned* __restrict__ sgw,
                                             const unsigned char* __restrict__ sgb,
                                             unsigned* __restrict__ csr,
                                             int* __restrict__ rowp,
                                             float* __restrict__ ndst) {
    __shared__ unsigned se[CAP];
    __shared__ unsigned char sd8[CAP];
    __shared__ unsigned dh[256];
    __shared__ unsigned dcur[256];
    __shared__ int sscan[256];
    const int b = blockIdx.x, t = threadIdx.x;
    const int cnt = (int)(cursor[b] - (unsigned)b * CAP);
    const int base = csrb[b];
    for (int i = t; i < cnt; i += 256) {
        se[i] = sgw[(size_t)b * CAP + i];
        sd8[i] = sgb[(size_t)b * CAP + i];
    }
    dh[t] = 0;
    __syncthreads();
    for (int i = t; i < cnt; i += 256) atomicAdd(&dh[sd8[i]], 1u);
    __syncthreads();
    int v = (int)dh[t];
    sscan[t] = v;
    __syncthreads();
    for (int off = 1; off < 256; off <<= 1) {
        int a = (t >= off) ? sscan[t - off] : 0;
        __syncthreads();
        sscan[t] += a;
        __syncthreads();
    }
    dcur[t] = (unsigned)(sscan[t] - v);
    const int node = b * 256 + t;
    if (node < N_NODES) {
        rowp[node] = base + (sscan[t] - v);
        ndst[node] = rsqrtf((float)max((unsigned)v, 1u));
    }
    __syncthreads();
    for (int i = t; i < cnt; i += 256) {
        unsigned pos = atomicAdd(&dcur[sd8[i]], 1u);
        csr[(size_t)base + pos] = se[i];
    }
}

// K7: W01 = W0 @ W1; block 92: bW1 = b0 @ W1
__global__ __launch_bounds__(128) void k_w01(const float* __restrict__ W0,
                                             const float* __restrict__ W1,
                                             const float* __restrict__ b0,
                                             float* __restrict__ w01,
                                             float* __restrict__ bw1) {
    const int t = threadIdx.x;
    const int k = blockIdx.x;
    float acc = 0.0f;
    if (k < F_IN) {
        for (int j = 0; j < WIDTH; ++j)
            acc = fmaf(W0[k * WIDTH + j], W1[j * WIDTH + t], acc);
        w01[k * WIDTH + t] = acc;
    } else {
        for (int j = 0; j < WIDTH; ++j)
            acc = fmaf(b0[j], W1[j * WIDTH + t], acc);
        bw1[t] = acc;
    }
}

// K7b: pack W01 (K-pad to 96, rows 92..95 zero) and W2 into fp16 B-frags
__global__ __launch_bounds__(256) void k_prepW(const float* __restrict__ w01,
                                               const float* __restrict__ W2,
                                               unsigned* __restrict__ w01p,
                                               unsigned* __restrict__ w2p) {
    int idx = blockIdx.x * 256 + threadIdx.x;
    if (idx < 6144) {
        int q = idx & 3, lane = (idx >> 2) & 63;
        int rest = idx >> 8;
        int kb = rest % 3, t = rest / 3;
        int k = kb * 32 + ((lane >> 4) * 8) + 2 * q;
        int n = t * 16 + (lane & 15);
        float lo = (k < F_IN) ? w01[k * WIDTH + n] : 0.f;
        float hi = (k + 1 < F_IN) ? w01[(k + 1) * WIDTH + n] : 0.f;
        w01p[idx] = (unsigned)f2h(lo) | ((unsigned)f2h(hi) << 16);
    } else if (idx < 10240) {
        int i2 = idx - 6144;
        int q = i2 & 3, lane = (i2 >> 2) & 63;
        int rest = i2 >> 8;
        int kb = rest & 3, t = rest >> 2;
        int k = kb * 32 + ((lane >> 4) * 8) + 2 * q;
        int n = t * 16 + (lane & 15);
        float lo = W2[k * F_OUT + n];
        float hi = W2[(k + 1) * F_OUT + n];
        w2p[i2] = (unsigned)f2h(lo) | ((unsigned)f2h(hi) << 16);
    }
}

// K8: G[n][0..95] = sum_in-edges X_bf16[src]*w.  Wave=node; 4 edges in parallel:
// es=lane>>4 picks edge slot, ci=lane&15 picks 3-word channel block (6 ch/lane).
// One dwordx3 load serves 4 edges/wave-instr; 2-step shfl reduce at end.
__global__ __launch_bounds__(256) void k_gatherG(const int* __restrict__ rowp,
                                                 const unsigned* __restrict__ csr,
                                                 const unsigned* __restrict__ xb,
                                                 float* __restrict__ g) {
    __shared__ unsigned sb[4][64];
    const int wid = threadIdx.x >> 6;
    const int lane = threadIdx.x & 63;
    const int es = lane >> 4;          // edge slot 0..3
    const int ci = lane & 15;          // channel block 0..15
    const int ci3 = ci * 3;
    unsigned* my = sb[wid];
    const int n = blockIdx.x * 4 + wid;
    const int start = rowp[n], end = rowp[n + 1];
    float acc[6] = {0.f, 0.f, 0.f, 0.f, 0.f, 0.f};
    for (int base = start; base < end; base += 64) {
        const int m = min(64, end - base);
        my[lane] = (lane < m) ? csr[base + lane] : 0u;   // pad w=0
#pragma unroll 2
        for (int j0 = 0; j0 < m; j0 += 4) {
            unsigned e = my[j0 + es];
            float w = csr_w(e);
            const unsigned* row = xb + (size_t)(e & 0xFFFFu) * XPITCH + ci3;
            uint3 a = *(const uint3*)row;
            acc[0] = fmaf(bflo(a.x), w, acc[0]);
            acc[1] = fmaf(bfhi(a.x), w, acc[1]);
            acc[2] = fmaf(bflo(a.y), w, acc[2]);
            acc[3] = fmaf(bfhi(a.y), w, acc[3]);
            acc[4] = fmaf(bflo(a.z), w, acc[4]);
            acc[5] = fmaf(bfhi(a.z), w, acc[5]);
        }
    }
#pragma unroll
    for (int k = 0; k < 6; ++k) {
        acc[k] += __shfl_xor(acc[k], 16);
        acc[k] += __shfl_xor(acc[k], 32);
    }
    if (lane < 16) {
        float* go = g + (size_t)n * 96 + lane * 6;
        go[0] = acc[0]; go[1] = acc[1]; go[2] = acc[2];
        go[3] = acc[3]; go[4] = acc[4]; go[5] = acc[5];
    }
}

// K9: MFMA layer1 (16 rows/wave): GEMM1 + bias/relu -> GEMM2 -> bf16 hs2.
// S comes from g channel 92 (unit-column trick).
__global__ __launch_bounds__(256) void k_layer1(const float* __restrict__ g,
                                                const float* __restrict__ ndst,
                                                const unsigned* __restrict__ w01p,
                                                const unsigned* __restrict__ w2p,
                                                const float* __restrict__ bw1,
                                                const float* __restrict__ b1,
                                                unsigned short* __restrict__ hs2h) {
    __shared__ unsigned short x2[4][16][136];
    __shared__ float svs[4][16];
    const int wid = threadIdx.x >> 6, lane = threadIdx.x & 63;
    const int row0 = blockIdx.x * 64 + wid * 16;
    const int mn = lane & 15;
    const int kq = lane >> 4;
    if (lane < 16) {
        int r = row0 + lane;
        svs[wid][lane] = (r < N_NODES) ? g[(size_t)r * 96 + 92] * ndst[r] : 0.f;
    }
    const float nd = ndst[min(row0 + mn, N_NODES - 1)];
    const float* grow = g + (size_t)min(row0 + mn, N_NODES - 1) * 96;
    half8v a1[3];
#pragma unroll
    for (int kb = 0; kb < 3; ++kb) {
        const float4 p0 = *(const float4*)(grow + kb * 32 + kq * 8);
        const float4 p1 = *(const float4*)(grow + kb * 32 + kq * 8 + 4);
        a1[kb][0] = (_Float16)(p0.x * nd); a1[kb][1] = (_Float16)(p0.y * nd);
        a1[kb][2] = (_Float16)(p0.z * nd); a1[kb][3] = (_Float16)(p0.w * nd);
        a1[kb][4] = (_Float16)(p1.x * nd); a1[kb][5] = (_Float16)(p1.y * nd);
        a1[kb][6] = (_Float16)(p1.z * nd); a1[kb][7] = (_Float16)(p1.w * nd);
    }
    for (int t = 0; t < 8; ++t) {
        const float bwv = bw1[t * 16 + mn];
        const float b1v = b1[t * 16 + mn];
        f32x4 acc = {0.f, 0.f, 0.f, 0.f};
        const unsigned* wp = w01p + ((size_t)t * 3 * 64 + lane) * 4;
#pragma unroll
        for (int kb = 0; kb < 3; ++kb) {
            half8v bf = *(const half8v*)(wp + (size_t)kb * 256);
            acc = __builtin_amdgcn_mfma_f32_16x16x32_f16(a1[kb], bf, acc, 0, 0, 0);
        }
#pragma unroll
        for (int r = 0; r < 4; ++r) {
            float v = acc[r] + svs[wid][kq * 4 + r] * bwv + b1v;
            x2[wid][kq * 4 + r][t * 16 + mn] = f2h(fmaxf(v, 0.f));
        }
    }
    half8v a2[4];
#pragma unroll
    for (int kb = 0; kb < 4; ++kb)
        a2[kb] = *(const half8v*)&x2[wid][mn][kb * 32 + kq * 8];
    for (int t2 = 0; t2 < 4; ++t2) {
        f32x4 acc = {0.f, 0.f, 0.f, 0.f};
        const unsigned* wp = w2p + ((size_t)t2 * 4 * 64 + lane) * 4;
#pragma unroll
        for (int kb = 0; kb < 4; ++kb) {
            half8v bf = *(const half8v*)(wp + (size_t)kb * 256);
            acc = __builtin_amdgcn_mfma_f32_16x16x32_f16(a2[kb], bf, acc, 0, 0, 0);
        }
#pragma unroll
        for (int r = 0; r < 4; ++r) {
            int row = row0 + kq * 4 + r;
            if (row < N_NODES)
                hs2h[(size_t)row * 64 + t2 * 16 + mn] = f2bf(acc[r]);
        }
    }
}

// K10: agg2[n][0..63] = sum_in-edges hs2[src]*w.  Wave=node; 8 edges in parallel:
// es=lane>>3, ci=lane&7 (dwordx4 = 8 ch/lane); 3-step shfl reduce.
__global__ __launch_bounds__(256) void k_gather2(const int* __restrict__ rowp,
                                                 const unsigned* __restrict__ csr,
                                                 const unsigned* __restrict__ hs2u,
                                                 float* __restrict__ agg2) {
    __shared__ unsigned sb[4][64];
    const int wid = threadIdx.x >> 6;
    const int lane = threadIdx.x & 63;
    const int es = lane >> 3;          // edge slot 0..7
    const int ci = lane & 7;           // channel block 0..7
    unsigned* my = sb[wid];
    const int n = blockIdx.x * 4 + wid;
    const int start = rowp[n], end = rowp[n + 1];
    float acc[8] = {0.f, 0.f, 0.f, 0.f, 0.f, 0.f, 0.f, 0.f};
    for (int base = start; base < end; base += 64) {
        const int m = min(64, end - base);
        my[lane] = (lane < m) ? csr[base + lane] : 0u;
#pragma unroll 2
        for (int j0 = 0; j0 < m; j0 += 8) {
            unsigned e = my[j0 + es];
            float w = csr_w(e);
            const uint4 a = *(const uint4*)(hs2u + (size_t)(e & 0xFFFFu) * 32 + ci * 4);
            acc[0] = fmaf(bflo(a.x), w, acc[0]);
            acc[1] = fmaf(bfhi(a.x), w, acc[1]);
            acc[2] = fmaf(bflo(a.y), w, acc[2]);
            acc[3] = fmaf(bfhi(a.y), w, acc[3]);
            acc[4] = fmaf(bflo(a.z), w, acc[4]);
            acc[5] = fmaf(bfhi(a.z), w, acc[5]);
            acc[6] = fmaf(bflo(a.w), w, acc[6]);
            acc[7] = fmaf(bfhi(a.w), w, acc[7]);
        }
    }
#pragma unroll
    for (int k = 0; k < 8; ++k) {
        acc[k] += __shfl_xor(acc[k], 8);
        acc[k] += __shfl_xor(acc[k], 16);
        acc[k] += __shfl_xor(acc[k], 32);
    }
    if (lane < 8) {
        float4* ao = (float4*)(agg2 + (size_t)n * 64 + ci * 8);
        ao[0] = make_float4(acc[0], acc[1], acc[2], acc[3]);
        ao[1] = make_float4(acc[4], acc[5], acc[6], acc[7]);
    }
}

// K11: per-graph mean pooling via sorted-gid segments
__global__ __launch_bounds__(64) void k_pool(const float* __restrict__ agg2,
                                             const float* __restrict__ ndst,
                                             const float* __restrict__ b2,
                                             const int* __restrict__ gid,
                                             float* __restrict__ out) {
    const int g = blockIdx.x;
    const int t = threadIdx.x;
    int lo = 0, hi = N_NODES;
    while (lo < hi) { int mid = (lo + hi) >> 1; if (gid[mid] < g) lo = mid + 1; else hi = mid; }
    const int start = lo;
    hi = N_NODES;
    while (lo < hi) { int mid = (lo + hi) >> 1; if (gid[mid] < g + 1) lo = mid + 1; else hi = mid; }
    const int end = lo;
    float sum = 0.0f;
    for (int n = start; n < end; ++n)
        sum = fmaf(agg2[n * F_OUT + t], ndst[n], sum);
    out[g * F_OUT + t] = (end > start) ? (sum / (float)(end - start) + b2[t]) : 0.0f;
}

extern "C" void kernel_launch(void* const* d_in, const int* in_sizes, int n_in,
                              void* d_out, int out_size, void* d_ws, size_t ws_size,
                              hipStream_t stream) {
    const float* af  = (const float*)d_in[0];
    const float* bl  = (const float*)d_in[1];
    const int*   src = (const int*)d_in[2];
    const int*   dst = (const int*)d_in[3];
    const int*   gid = (const int*)d_in[4];
    const float* W0  = (const float*)d_in[5];
    const float* b0  = (const float*)d_in[6];
    const float* W1  = (const float*)d_in[7];
    const float* b1  = (const float*)d_in[8];
    const float* W2  = (const float*)d_in[9];
    const float* b2  = (const float*)d_in[10];
    float* out = (float*)d_out;
    float* ws  = (float*)d_ws;

    unsigned*       cursor = (unsigned*)(ws + CURS);
    int*            csrb   = (int*)(ws + CSRB);
    float*          nsrc   = ws + NSRC;
    float*          ndst   = ws + NDST;
    int*            rowp   = (int*)(ws + ROWP);
    unsigned char*  h_src  = (unsigned char*)(ws + HSR);
    unsigned*       sgw    = (unsigned*)(ws + SGW);
    unsigned char*  sgb    = (unsigned char*)(ws + SGB);
    unsigned*       csr    = (unsigned*)(ws + CSR);
    unsigned*       xb     = (unsigned*)(ws + XB);
    float*          w01    = ws + W01;
    float*          bw1    = ws + BW1;
    unsigned*       w01p   = (unsigned*)(ws + W01P);
    unsigned*       w2p    = (unsigned*)(ws + W2P);
    float*          g      = ws + GAGG;
    unsigned*       hs2u   = (unsigned*)(ws + HS2);
    unsigned short* hs2h   = (unsigned short*)(ws + HS2);
    float*          agg2   = ws + AGG2;

    k_init<<<1, 256, 0, stream>>>(cursor);
    k_srcHist<<<NBLK_E, 256, 0, stream>>>(src, h_src);
    k_packX<<<(N_NODES * XPITCH) / 256, 256, 0, stream>>>(af, xb);
    k_nsrc<<<BKT, 256, 0, stream>>>(h_src, nsrc);
    k_bin<<<NBIN, 256, 0, stream>>>(bl, src, dst, nsrc, cursor, sgw, sgb);
    k_bscan<<<1, 256, 0, stream>>>(cursor, csrb, rowp);
    k_csr<<<BKT, 256, 0, stream>>>(cursor, csrb, sgw, sgb, csr, rowp, ndst);
    k_w01<<<F_IN + 1, 128, 0, stream>>>(W0, W1, b0, w01, bw1);
    k_prepW<<<40, 256, 0, stream>>>(w01, W2, w01p, w2p);
    k_gatherG<<<N_NODES / 4, 256, 0, stream>>>(rowp, csr, xb, g);
    k_layer1<<<(N_NODES + 63) / 64, 256, 0, stream>>>(g, ndst, w01p, w2p, bw1, b1, hs2h);
    k_gather2<<<N_NODES / 4, 256, 0, stream>>>(rowp, csr, hs2u, agg2);
    k_pool<<<N_GRAPHS, 64, 0, stream>>>(agg2, ndst, b2, gid, out);
}